// Round 7
// baseline (607.778 us; speedup 1.0000x reference)
//
#include <hip/hip_runtime.h>
#include <hip/hip_bf16.h>
#include <math.h>

#define NTOK 384
#define HEADS 4

typedef __attribute__((ext_vector_type(8))) short bf16x8;
typedef __attribute__((ext_vector_type(4))) float f32x4;

__device__ __forceinline__ unsigned short f2b(float f) {
    union { float f; unsigned int u; } v; v.f = f;
    unsigned int r = (v.u + 0x7fff + ((v.u >> 16) & 1)) >> 16;  // RNE
    return (unsigned short)r;
}

// async 16B global -> LDS (wave-uniform LDS base; HW adds lane*16)
__device__ __forceinline__ void g2l16(const void* g, void* l) {
    __builtin_amdgcn_global_load_lds(
        (const __attribute__((address_space(1))) unsigned int*)g,
        (__attribute__((address_space(3))) unsigned int*)l, 16, 0, 0);
}

// ---------------------------------------------------------------------------
// gemm64: 64x64-tile MFMA bf16 GEMM, batched over z (r4-proven config).
// Block 256 thr = 4 waves (2x2). BK=64, triple-buffered LDS, depth-2
// counted-vmcnt pipeline (vmcnt(4) keeps next tile's 4 loads in flight
// across the barrier). Used for the attention GEMMs (QK^T, PV).
// ---------------------------------------------------------------------------
__device__ __forceinline__ void stage64(
    const unsigned short* __restrict__ g, int row0, int k0, int ld,
    char* region, int wid, int lane)
{
    int c = wid * 64 + lane;                 // chunk 0..255
    int row = c >> 2, p = c & 3;
    int kc = (p - (row >> 1)) & 3;
    g2l16(g + (long)(row0 + row) * ld + k0 + kc * 8,
          region + (wid * 64) * 16);         // wave-uniform base
}

__device__ __forceinline__ void stage_tile(
    const unsigned short* __restrict__ A, const unsigned short* __restrict__ B,
    int row0, int col0, int k0, int lda, int ldb,
    char* buf, int wid, int lane)
{
    stage64(A, row0, k0,      lda, buf,         wid, lane);
    stage64(A, row0, k0 + 32, lda, buf +  4096, wid, lane);
    stage64(B, col0, k0,      ldb, buf +  8192, wid, lane);
    stage64(B, col0, k0 + 32, ldb, buf + 12288, wid, lane);
    __builtin_amdgcn_sched_barrier(0);       // keep the 4 loads contiguous
}

__global__ __launch_bounds__(256, 3) void gemm64(
    const unsigned short* __restrict__ A, const unsigned short* __restrict__ B,
    const float* __restrict__ bias, void* __restrict__ Cv,
    int K, int lda, int ldb, int ldc,
    long sA, long sB, long sC, int relu, int out_bf16)
{
    __shared__ char smem[3][16384];          // per buf: A0|A1|B0|B1 (4KB each)
    A += (long)blockIdx.z * sA;
    B += (long)blockIdx.z * sB;
    const int t = threadIdx.x, lane = t & 63, wid = t >> 6;
    const int wm = wid >> 1, wn = wid & 1;
    const int r16 = lane & 15, quad = lane >> 4;
    const int row0 = blockIdx.y * 64, col0 = blockIdx.x * 64;

    f32x4 acc[2][2] = {};
    const int NT = K >> 6;                   // K is a multiple of 64 here

    stage_tile(A, B, row0, col0, 0, lda, ldb, smem[0], wid, lane);
    if (NT > 1)
        stage_tile(A, B, row0, col0, 64, lda, ldb, smem[1], wid, lane);

    int cur = 0, sb = 2;
    for (int kt = 0; kt < NT; ++kt) {
        if (kt + 1 < NT) asm volatile("s_waitcnt vmcnt(4)" ::: "memory");
        else             asm volatile("s_waitcnt vmcnt(0) lgkmcnt(0)" ::: "memory");
        __builtin_amdgcn_s_barrier();
        if (kt + 2 < NT) {
            stage_tile(A, B, row0, col0, (kt + 2) * 64, lda, ldb,
                       smem[sb], wid, lane);
            sb = (sb == 2) ? 0 : sb + 1;
        }
        const char* cb = smem[cur];
        cur = (cur == 2) ? 0 : cur + 1;
        #pragma unroll
        for (int h = 0; h < 2; ++h) {
            bf16x8 af[2], bfv[2];
            #pragma unroll
            for (int rt = 0; rt < 2; ++rt) {
                int row = wm * 32 + rt * 16 + r16;
                int p = (quad + (row >> 1)) & 3;
                af[rt] = *reinterpret_cast<const bf16x8*>(
                    cb + h * 4096 + row * 64 + p * 16);
            }
            #pragma unroll
            for (int ct = 0; ct < 2; ++ct) {
                int col = wn * 32 + ct * 16 + r16;
                int p = (quad + (col >> 1)) & 3;
                bfv[ct] = *reinterpret_cast<const bf16x8*>(
                    cb + 8192 + h * 4096 + col * 64 + p * 16);
            }
            #pragma unroll
            for (int rt = 0; rt < 2; ++rt)
                #pragma unroll
                for (int ct = 0; ct < 2; ++ct)
                    acc[rt][ct] = __builtin_amdgcn_mfma_f32_16x16x32_bf16(
                        af[rt], bfv[ct], acc[rt][ct], 0, 0, 0);
        }
    }

    float* Cf = (float*)Cv;
    unsigned short* Cb = (unsigned short*)Cv;
    const long zoff = (long)blockIdx.z * sC;
    #pragma unroll
    for (int rt = 0; rt < 2; ++rt) {
        #pragma unroll
        for (int ct = 0; ct < 2; ++ct) {
            f32x4 v = acc[rt][ct];
            int col = col0 + wn * 32 + ct * 16 + r16;
            float bi = bias ? bias[col] : 0.f;
            #pragma unroll
            for (int i = 0; i < 4; ++i) {
                v[i] += bi;
                if (relu) v[i] = fmaxf(v[i], 0.f);
            }
            int rbase = row0 + wm * 32 + rt * 16 + quad * 4;
            if (out_bf16) {
                #pragma unroll
                for (int i = 0; i < 4; ++i)
                    Cb[zoff + (long)(rbase + i) * ldc + col] = f2b(v[i]);
            } else {
                #pragma unroll
                for (int i = 0; i < 4; ++i)
                    Cf[zoff + (long)(rbase + i) * ldc + col] = v[i];
            }
        }
    }
}

// ---------------------------------------------------------------------------
// gemm128: 128x128-tile MFMA bf16 GEMM for the WEIGHT gemms (qkv, out-proj,
// ff1, ff2). 512 thr = 8 waves (2x4); per wave a 64x32 output = 8 accs.
// Same rotated-LDS layout and depth-2 counted-vmcnt pipeline as gemm64, but
// 128 MFMA per K-iter against the same per-iter barrier overhead (8x the
// MFMA-per-barrier of gemm64 — these GEMMs are overhead-bound, ~1300cy/iter
// at 16 MFMA). BK=64; 3 x 32KB LDS = 96KB -> 1 block/CU (grids here are
// under-occupied anyway; M=384 = 3 row-tiles exactly).
// Optional transposed-V epilogue (vt) for col0 >= dv2, as before.
// ---------------------------------------------------------------------------
__device__ __forceinline__ void stage128(
    const unsigned short* __restrict__ g, int row0, int k0, int ld,
    char* region, int tid)
{
    int row = tid >> 2, p = tid & 3;         // row 0..127
    int kc = (p - (row >> 1)) & 3;
    g2l16(g + (long)(row0 + row) * ld + k0 + kc * 8,
          region + ((tid >> 6) * 64) * 16);  // wave-uniform base
}

__device__ __forceinline__ void stage_tile128(
    const unsigned short* __restrict__ A, const unsigned short* __restrict__ B,
    int row0, int col0, int k0, int lda, int ldb,
    char* buf, int tid)
{
    stage128(A, row0, k0,      lda, buf,          tid);
    stage128(A, row0, k0 + 32, lda, buf +  8192,  tid);
    stage128(B, col0, k0,      ldb, buf + 16384,  tid);
    stage128(B, col0, k0 + 32, ldb, buf + 24576,  tid);
    __builtin_amdgcn_sched_barrier(0);
}

__global__ __launch_bounds__(512, 1) void gemm128(
    const unsigned short* __restrict__ A, const unsigned short* __restrict__ B,
    const float* __restrict__ bias, void* __restrict__ Cv,
    int K, int lda, int ldb, int ldc, int relu, int out_bf16,
    unsigned short* __restrict__ vt, int dv2)
{
    __shared__ char smem[3][32768];          // per buf: A0|A1|B0|B1 (8KB each)
    const int t = threadIdx.x, lane = t & 63, wid = t >> 6;
    const int wm = wid >> 2, wn = wid & 3;   // 2 x 4 wave grid
    const int r16 = lane & 15, quad = lane >> 4;
    const int row0 = blockIdx.y * 128, col0 = blockIdx.x * 128;

    f32x4 acc[4][2] = {};
    const int NT = K >> 6;

    stage_tile128(A, B, row0, col0, 0, lda, ldb, smem[0], t);
    if (NT > 1)
        stage_tile128(A, B, row0, col0, 64, lda, ldb, smem[1], t);

    int cur = 0, sb = 2;
    for (int kt = 0; kt < NT; ++kt) {
        if (kt + 1 < NT) asm volatile("s_waitcnt vmcnt(4)" ::: "memory");
        else             asm volatile("s_waitcnt vmcnt(0) lgkmcnt(0)" ::: "memory");
        __builtin_amdgcn_s_barrier();
        if (kt + 2 < NT) {
            stage_tile128(A, B, row0, col0, (kt + 2) * 64, lda, ldb,
                          smem[sb], t);
            sb = (sb == 2) ? 0 : sb + 1;
        }
        const char* cb = smem[cur];
        cur = (cur == 2) ? 0 : cur + 1;
        #pragma unroll
        for (int h = 0; h < 2; ++h) {
            bf16x8 af[4], bfv[2];
            #pragma unroll
            for (int rt = 0; rt < 4; ++rt) {
                int row = wm * 64 + rt * 16 + r16;
                int p = (quad + (row >> 1)) & 3;
                af[rt] = *reinterpret_cast<const bf16x8*>(
                    cb + h * 8192 + row * 64 + p * 16);
            }
            #pragma unroll
            for (int ct = 0; ct < 2; ++ct) {
                int col = wn * 32 + ct * 16 + r16;
                int p = (quad + (col >> 1)) & 3;
                bfv[ct] = *reinterpret_cast<const bf16x8*>(
                    cb + 16384 + h * 8192 + col * 64 + p * 16);
            }
            #pragma unroll
            for (int rt = 0; rt < 4; ++rt)
                #pragma unroll
                for (int ct = 0; ct < 2; ++ct)
                    acc[rt][ct] = __builtin_amdgcn_mfma_f32_16x16x32_bf16(
                        af[rt], bfv[ct], acc[rt][ct], 0, 0, 0);
        }
    }

    float* Cf = (float*)Cv;
    unsigned short* Cb = (unsigned short*)Cv;
    const int vwrite = (vt != nullptr) && (col0 >= dv2);
    #pragma unroll
    for (int rt = 0; rt < 4; ++rt) {
        #pragma unroll
        for (int ct = 0; ct < 2; ++ct) {
            f32x4 v = acc[rt][ct];
            int col = col0 + wn * 32 + ct * 16 + r16;
            float bi = bias ? bias[col] : 0.f;
            #pragma unroll
            for (int i = 0; i < 4; ++i) {
                v[i] += bi;
                if (relu) v[i] = fmaxf(v[i], 0.f);
            }
            int rbase = row0 + wm * 64 + rt * 16 + quad * 4;
            if (vwrite) {
                ushort4 p;
                p.x = f2b(v[0]); p.y = f2b(v[1]); p.z = f2b(v[2]); p.w = f2b(v[3]);
                *reinterpret_cast<ushort4*>(vt + (long)(col - dv2) * NTOK + rbase) = p;
            } else if (out_bf16) {
                #pragma unroll
                for (int i = 0; i < 4; ++i)
                    Cb[(long)(rbase + i) * ldc + col] = f2b(v[i]);
            } else {
                #pragma unroll
                for (int i = 0; i < 4; ++i)
                    Cf[(long)(rbase + i) * ldc + col] = v[i];
            }
        }
    }
}

// ---------------------------------------------------------------------------
// Fused fp32 -> bf16 conversion of all 8 weight tensors. 16 elems/thread.
// ---------------------------------------------------------------------------
#define WO0 0u
#define WO1 3538944u
#define WO2 4718592u
#define WO3 7864320u
#define WO4 11010048u
#define WO5 25165824u
#define WO6 29884416u
#define WO7 36175872u
#define WTOT 42467328u

__global__ __launch_bounds__(256) void convert_weights(
    const float* __restrict__ s0, const float* __restrict__ s1,
    const float* __restrict__ s2, const float* __restrict__ s3,
    const float* __restrict__ s4, const float* __restrict__ s5,
    const float* __restrict__ s6, const float* __restrict__ s7,
    unsigned short* __restrict__ dst)
{
    unsigned int e = (blockIdx.x * 256u + threadIdx.x) * 16u;
    if (e >= WTOT) return;
    const float* src; unsigned int local;
    if      (e < WO1) { src = s0; local = e - WO0; }
    else if (e < WO2) { src = s1; local = e - WO1; }
    else if (e < WO3) { src = s2; local = e - WO2; }
    else if (e < WO4) { src = s3; local = e - WO3; }
    else if (e < WO5) { src = s4; local = e - WO4; }
    else if (e < WO6) { src = s5; local = e - WO5; }
    else if (e < WO7) { src = s6; local = e - WO6; }
    else              { src = s7; local = e - WO7; }
    float4 v0 = *reinterpret_cast<const float4*>(src + local);
    float4 v1 = *reinterpret_cast<const float4*>(src + local + 4);
    float4 v2 = *reinterpret_cast<const float4*>(src + local + 8);
    float4 v3 = *reinterpret_cast<const float4*>(src + local + 12);
    uint4 o0, o1;
    o0.x = (unsigned)f2b(v0.x) | ((unsigned)f2b(v0.y) << 16);
    o0.y = (unsigned)f2b(v0.z) | ((unsigned)f2b(v0.w) << 16);
    o0.z = (unsigned)f2b(v1.x) | ((unsigned)f2b(v1.y) << 16);
    o0.w = (unsigned)f2b(v1.z) | ((unsigned)f2b(v1.w) << 16);
    o1.x = (unsigned)f2b(v2.x) | ((unsigned)f2b(v2.y) << 16);
    o1.y = (unsigned)f2b(v2.z) | ((unsigned)f2b(v2.w) << 16);
    o1.z = (unsigned)f2b(v3.x) | ((unsigned)f2b(v3.y) << 16);
    o1.w = (unsigned)f2b(v3.z) | ((unsigned)f2b(v3.w) << 16);
    *reinterpret_cast<uint4*>(dst + e) = o0;
    *reinterpret_cast<uint4*>(dst + e + 8) = o1;
}

// ---------------------------------------------------------------------------
// Softmax over rows of length 384 (one wave per row); fp32 in, bf16 out.
// ---------------------------------------------------------------------------
__global__ __launch_bounds__(64) void softmax_rows(
    const float* __restrict__ S, unsigned short* __restrict__ P, float scale)
{
    const float* p = S + (long)blockIdx.x * NTOK;
    unsigned short* q = P + (long)blockIdx.x * NTOK;
    const int t = threadIdx.x;
    float vals[6];
    float vmax = -1e30f;
    #pragma unroll
    for (int i = 0; i < 6; ++i) {
        vals[i] = p[t + i * 64] * scale;
        vmax = fmaxf(vmax, vals[i]);
    }
    for (int off = 32; off; off >>= 1) vmax = fmaxf(vmax, __shfl_down(vmax, off));
    vmax = __shfl(vmax, 0);
    float sum = 0.f;
    #pragma unroll
    for (int i = 0; i < 6; ++i) { vals[i] = __expf(vals[i] - vmax); sum += vals[i]; }
    for (int off = 32; off; off >>= 1) sum += __shfl_down(sum, off);
    sum = __shfl(sum, 0);
    float inv = 1.f / sum;
    #pragma unroll
    for (int i = 0; i < 6; ++i) q[t + i * 64] = f2b(vals[i] * inv);
}

// ---------------------------------------------------------------------------
// x = LayerNorm(x + gb + y) * s + b  (fp32) + bf16 copy xb. gb is the gemm
// output bias (folded here). Row values cached in registers.
// ---------------------------------------------------------------------------
__global__ __launch_bounds__(256) void add_ln(
    float* __restrict__ x, unsigned short* __restrict__ xb,
    const float* __restrict__ y,
    const float* __restrict__ gb,
    const float* __restrict__ s, const float* __restrict__ b, int d)
{
    float* xr = x + (long)blockIdx.x * d;
    unsigned short* xbr = xb + (long)blockIdx.x * d;
    const float* yr = y + (long)blockIdx.x * d;
    const int t = threadIdx.x;
    float vv[6];                             // d/256 <= 6 (d in {768,1536})
    float s1 = 0.f, s2 = 0.f;
    #pragma unroll
    for (int j = 0; j < 6; ++j) {
        int i = t + j * 256;
        if (j * 256 < d) {
            float v = xr[i] + gb[i] + yr[i];
            vv[j] = v;
            s1 += v; s2 += v * v;
        }
    }
    for (int off = 32; off; off >>= 1) { s1 += __shfl_down(s1, off); s2 += __shfl_down(s2, off); }
    __shared__ float r1[4], r2[4];
    int w = t >> 6;
    if ((t & 63) == 0) { r1[w] = s1; r2[w] = s2; }
    __syncthreads();
    if (t == 0) {
        float a = 0.f, c = 0.f;
        for (int i = 0; i < 4; ++i) { a += r1[i]; c += r2[i]; }
        r1[0] = a; r2[0] = c;
    }
    __syncthreads();
    float mean = r1[0] / d;
    float var = r2[0] / d - mean * mean;
    float rstd = rsqrtf(var + 1e-5f);
    #pragma unroll
    for (int j = 0; j < 6; ++j) {
        int i = t + j * 256;
        if (j * 256 < d) {
            float v = (vv[j] - mean) * rstd * s[i] + b[i];
            xr[i] = v;
            xbr[i] = f2b(v);
        }
    }
}

// ---------------------------------------------------------------------------
// init / concat (write fp32 + bf16 copies)
// ---------------------------------------------------------------------------
__global__ void initx_k(const float* __restrict__ src, float* __restrict__ dst,
                        unsigned short* __restrict__ dstb, int n)
{
    int i = blockIdx.x * blockDim.x + threadIdx.x;
    if (i < n) { float v = src[i]; dst[i] = v; dstb[i] = f2b(v); }
}

__global__ void concat_k(const float* __restrict__ te, const float* __restrict__ ve,
                         float* __restrict__ all, unsigned short* __restrict__ allb)
{
    int i = blockIdx.x * blockDim.x + threadIdx.x;
    if (i >= NTOK * 1536) return;
    int r = i / 1536, c = i % 1536;
    float v = (c < 768) ? te[r * 768 + c] : ve[r * 768 + (c - 768)];
    all[i] = v;
    allb[i] = f2b(v);
}

// ---------------------------------------------------------------------------
// head kernels (fp32)
// ---------------------------------------------------------------------------
__global__ __launch_bounds__(256) void head_ac(
    const float* __restrict__ all, const float* __restrict__ lin_w,
    const float* __restrict__ lin_b, float* __restrict__ a, float* __restrict__ c)
{
    const int i = blockIdx.x, t = threadIdx.x;
    const float* xr = all + (long)i * 1536;
    float s0 = 0.f, s1 = 0.f, s2 = 0.f, s3 = 0.f;
    for (int e = t; e < 1536; e += 256) {
        float v = xr[e];
        s0 += v * lin_w[e];
        s1 += v * lin_w[3072 + e];
        s2 += v * lin_w[1536 + e];
        s3 += v * lin_w[4608 + e];
    }
    for (int off = 32; off; off >>= 1) {
        s0 += __shfl_down(s0, off); s1 += __shfl_down(s1, off);
        s2 += __shfl_down(s2, off); s3 += __shfl_down(s3, off);
    }
    __shared__ float r[4][4];
    int w = t >> 6;
    if ((t & 63) == 0) { r[0][w] = s0; r[1][w] = s1; r[2][w] = s2; r[3][w] = s3; }
    __syncthreads();
    if (t == 0) {
        float t0 = 0.f, t1 = 0.f, t2 = 0.f, t3 = 0.f;
        for (int k = 0; k < 4; ++k) { t0 += r[0][k]; t1 += r[1][k]; t2 += r[2][k]; t3 += r[3][k]; }
        a[i * 2 + 0] = t0 + lin_b[0];
        a[i * 2 + 1] = t1 + lin_b[1];
        c[i * 2 + 0] = t2;
        c[i * 2 + 1] = t3;
    }
}

__global__ __launch_bounds__(384) void head_probs(
    const float* __restrict__ a, const float* __restrict__ c,
    const int* __restrict__ gt, float* __restrict__ probs,
    float* __restrict__ rowsum, float* __restrict__ rowcell)
{
    const int i = blockIdx.x, j = threadIdx.x;
    float l0 = a[i * 2 + 0] + c[j * 2 + 0];
    float l1 = a[i * 2 + 1] + c[j * 2 + 1];
    float m = fmaxf(l0, l1);
    float e0 = __expf(l0 - m), e1 = __expf(l1 - m);
    float inv = 1.f / (e0 + e1);
    float p0 = e0 * inv, p1 = e1 * inv;
    long base = ((long)i * NTOK + j) * 2;
    probs[base] = p0;
    probs[base + 1] = p1;
    float m2 = fmaxf(p0, p1);
    float z = m2 + __logf(__expf(p0 - m2) + __expf(p1 - m2));
    int g = gt[i * NTOK + j];
    float cell = z - (g ? p1 : p0);
    float cs = cell, ps = p1;
    for (int off = 32; off; off >>= 1) { cs += __shfl_down(cs, off); ps += __shfl_down(ps, off); }
    __shared__ float rc[6], rs[6];
    int w = j >> 6;
    if ((j & 63) == 0) { rc[w] = cs; rs[w] = ps; }
    __syncthreads();
    if (j == 0) {
        float csum = 0.f, psum = 0.f;
        for (int k = 0; k < 6; ++k) { csum += rc[k]; psum += rs[k]; }
        rowcell[i] = csum * (1.f / NTOK);
        rowsum[i] = psum;
    }
}

__global__ __launch_bounds__(64) void colsum_k(const float* __restrict__ probs,
                                               float* __restrict__ colsum)
{
    const int j = blockIdx.x, t = threadIdx.x;
    float s = 0.f;
    for (int i = t; i < NTOK; i += 64)
        s += probs[((long)i * NTOK + j) * 2 + 1];
    for (int off = 32; off; off >>= 1) s += __shfl_down(s, off);
    if (t == 0) colsum[j] = s;
}

__global__ __launch_bounds__(384) void finalize_k(
    const float* __restrict__ rowcell, const float* __restrict__ rowsum,
    const float* __restrict__ colsum, float* __restrict__ out)
{
    const int t = threadIdx.x;
    float cls = rowcell[t];
    float ee = (t < NTOK - 1) ? fabsf(rowsum[t] + colsum[t] - 1.f) : 0.f;
    for (int off = 32; off; off >>= 1) { cls += __shfl_down(cls, off); ee += __shfl_down(ee, off); }
    __shared__ float rc[6], re[6];
    int w = t >> 6;
    if ((t & 63) == 0) { rc[w] = cls; re[w] = ee; }
    __syncthreads();
    if (t == 0) {
        float a = 0.f, b = 0.f;
        for (int k = 0; k < 6; ++k) { a += rc[k]; b += re[k]; }
        out[NTOK * NTOK * 2 + 0] = a;
        out[NTOK * NTOK * 2 + 1] = b;
    }
}

// ---------------------------------------------------------------------------
// host-side encoder driver: gemm128 for weight gemms, gemm64 for attention
// ---------------------------------------------------------------------------
static void run_encoder(float* x, unsigned short* xb, int d,
                        const unsigned short* wq, const unsigned short* wo,
                        const unsigned short* w1, const unsigned short* w2,
                        const float* qkv_b, const float* out_b,
                        const float* ln1_s, const float* ln1_b,
                        const float* ff1_b, const float* ff2_b,
                        const float* ln2_s, const float* ln2_b,
                        unsigned short* qkvb, float* sc, unsigned short* attnb,
                        unsigned short* vtb, unsigned short* ob,
                        unsigned short* t1b, float* t2,
                        hipStream_t stream)
{
    const int dq = 3 * d;
    const int hd = d / HEADS;
    const float scale = 1.0f / sqrtf((float)hd);
    for (int l = 0; l < 2; ++l) {
        // qkv = x @ Wqkv^T + b (bf16; V block written transposed to vtb)
        gemm128<<<dim3(dq / 128, NTOK / 128), 512, 0, stream>>>(
            xb, wq + (long)l * dq * d, qkv_b + l * dq, qkvb,
            d, d, d, dq, 0, 1, vtb, 2 * d);
        // scores = Q @ K^T (fp32), batched over heads
        gemm64<<<dim3(6, 6, HEADS), 256, 0, stream>>>(
            qkvb, qkvb + d, nullptr, sc,
            hd, dq, dq, NTOK, (long)hd, (long)hd, (long)NTOK * NTOK, 0, 0);
        softmax_rows<<<HEADS * NTOK, 64, 0, stream>>>(sc, attnb, scale);
        // o = attn @ V^T (bf16), batched over heads
        gemm64<<<dim3(hd / 64, 6, HEADS), 256, 0, stream>>>(
            attnb, vtb, nullptr, ob,
            NTOK, NTOK, NTOK, d, (long)NTOK * NTOK, (long)hd * NTOK, (long)hd,
            0, 1);
        // out-proj (fp32) + LN (bias folded into add_ln)
        gemm128<<<dim3(d / 128, NTOK / 128), 512, 0, stream>>>(
            ob, wo + (long)l * d * d, nullptr, t2,
            d, d, d, d, 0, 0, nullptr, 0);
        add_ln<<<NTOK, 256, 0, stream>>>(x, xb, t2,
                                         out_b + l * d, ln1_s + l * d, ln1_b + l * d, d);
        // ff1 (relu, bf16)
        gemm128<<<dim3(2048 / 128, NTOK / 128), 512, 0, stream>>>(
            xb, w1 + (long)l * 2048 * d, ff1_b + l * 2048, t1b,
            d, d, d, 2048, 1, 1, nullptr, 0);
        // ff2 (fp32) + LN (bias folded into add_ln)
        gemm128<<<dim3(d / 128, NTOK / 128), 512, 0, stream>>>(
            t1b, w2 + (long)l * d * 2048, nullptr, t2,
            2048, 2048, 2048, d, 0, 0, nullptr, 0);
        add_ln<<<NTOK, 256, 0, stream>>>(x, xb, t2,
                                         ff2_b + l * d, ln2_s + l * d, ln2_b + l * d, d);
    }
}

extern "C" void kernel_launch(void* const* d_in, const int* in_sizes, int n_in,
                              void* d_out, int out_size, void* d_ws, size_t ws_size,
                              hipStream_t stream)
{
    const float* text_emb   = (const float*)d_in[0];
    const float* vision_emb = (const float*)d_in[1];
    const int*   gt         = (const int*)  d_in[2];
    const float* t_qkv_w = (const float*)d_in[3];
    const float* t_qkv_b = (const float*)d_in[4];
    const float* t_out_w = (const float*)d_in[5];
    const float* t_out_b = (const float*)d_in[6];
    const float* t_ln1_s = (const float*)d_in[7];
    const float* t_ln1_b = (const float*)d_in[8];
    const float* t_ff1_w = (const float*)d_in[9];
    const float* t_ff1_b = (const float*)d_in[10];
    const float* t_ff2_w = (const float*)d_in[11];
    const float* t_ff2_b = (const float*)d_in[12];
    const float* t_ln2_s = (const float*)d_in[13];
    const float* t_ln2_b = (const float*)d_in[14];
    const float* c_qkv_w = (const float*)d_in[15];
    const float* c_qkv_b = (const float*)d_in[16];
    const float* c_out_w = (const float*)d_in[17];
    const float* c_out_b = (const float*)d_in[18];
    const float* c_ln1_s = (const float*)d_in[19];
    const float* c_ln1_b = (const float*)d_in[20];
    const float* c_ff1_w = (const float*)d_in[21];
    const float* c_ff1_b = (const float*)d_in[22];
    const float* c_ff2_w = (const float*)d_in[23];
    const float* c_ff2_b = (const float*)d_in[24];
    const float* c_ln2_s = (const float*)d_in[25];
    const float* c_ln2_b = (const float*)d_in[26];
    const float* lin_w   = (const float*)d_in[27];
    const float* lin_b   = (const float*)d_in[28];
    float* out = (float*)d_out;

    // ---- workspace layout ----
    float* ws = (float*)d_ws;
    float* xt      = ws;                 // 384*768
    float* all     = xt + 294912;        // 384*1536
    float* t2      = all + 589824;       // 384*1536 (max)
    float* sc      = t2 + 589824;        // 4*384*384 fp32
    float* abuf    = sc + 589824;
    float* cbuf    = abuf + 768;
    float* rowsum  = cbuf + 768;
    float* rowcell = rowsum + 384;
    float* colsum  = rowcell + 384;      // fp32 total 2067072
    unsigned short* ub = (unsigned short*)(ws + 2067072);
    unsigned short* xtb   = ub;                  // 294912
    unsigned short* allb  = xtb + 294912;        // 589824
    unsigned short* qkvb  = allb + 589824;       // 384*4608
    unsigned short* attnb = qkvb + 1769472;      // 4*384*384
    unsigned short* vtb   = attnb + 589824;      // 1536*384 (max)
    unsigned short* ob    = vtb + 589824;        // 589824
    unsigned short* t1b   = ob + 589824;         // 384*2048
    unsigned short* wb    = t1b + 786432;        // 42467328 bf16 weights

    // ---- weight conversion (one fused launch, 16 elems/thread) ----
    convert_weights<<<(WTOT / 16 + 255) / 256, 256, 0, stream>>>(
        t_qkv_w, t_out_w, t_ff1_w, t_ff2_w,
        c_qkv_w, c_out_w, c_ff1_w, c_ff2_w, wb);

    // ---- text encoder (d = 768) ----
    initx_k<<<(294912 + 255) / 256, 256, 0, stream>>>(text_emb, xt, xtb, 294912);
    run_encoder(xt, xtb, 768,
                wb + WO0, wb + WO1, wb + WO2, wb + WO3,
                t_qkv_b, t_out_b, t_ln1_s, t_ln1_b,
                t_ff1_b, t_ff2_b, t_ln2_s, t_ln2_b,
                qkvb, sc, attnb, vtb, ob, t1b, t2, stream);

    // ---- concat -> combined encoder (d = 1536) ----
    concat_k<<<(589824 + 255) / 256, 256, 0, stream>>>(xt, vision_emb, all, allb);
    run_encoder(all, allb, 1536,
                wb + WO4, wb + WO5, wb + WO6, wb + WO7,
                c_qkv_b, c_out_b, c_ln1_s, c_ln1_b,
                c_ff1_b, c_ff2_b, c_ln2_s, c_ln2_b,
                qkvb, sc, attnb, vtb, ob, t1b, t2, stream);

    // ---- head ----
    head_ac<<<NTOK, 256, 0, stream>>>(all, lin_w, lin_b, abuf, cbuf);
    head_probs<<<NTOK, 384, 0, stream>>>(abuf, cbuf, gt, out, rowsum, rowcell);
    colsum_k<<<NTOK, 64, 0, stream>>>(out, colsum);
    finalize_k<<<1, 384, 0, stream>>>(rowcell, rowsum, colsum, out);
}

// Round 9
// 550.869 us; speedup vs baseline: 1.1033x; 1.1033x over previous
//
#include <hip/hip_runtime.h>
#include <hip/hip_bf16.h>
#include <math.h>

#define NTOK 384
#define HEADS 4

typedef __attribute__((ext_vector_type(8))) short bf16x8;
typedef __attribute__((ext_vector_type(4))) float f32x4;

__device__ __forceinline__ unsigned short f2b(float f) {
    union { float f; unsigned int u; } v; v.f = f;
    unsigned int r = (v.u + 0x7fff + ((v.u >> 16) & 1)) >> 16;  // RNE
    return (unsigned short)r;
}

// packed fp32 pair -> bf16x2 (RNE); lowers to v_cvt_pk_bf16_f32
__device__ __forceinline__ unsigned int cvt2(float a, float b) {
    __hip_bfloat162 h = __float22bfloat162_rn(make_float2(a, b));
    unsigned int u;
    __builtin_memcpy(&u, &h, 4);
    return u;
}

// async 16B global -> LDS (wave-uniform LDS base; HW adds lane*16)
__device__ __forceinline__ void g2l16(const void* g, void* l) {
    __builtin_amdgcn_global_load_lds(
        (const __attribute__((address_space(1))) unsigned int*)g,
        (__attribute__((address_space(3))) unsigned int*)l, 16, 0, 0);
}

// ---------------------------------------------------------------------------
// gemm64: 64x64-tile MFMA bf16 GEMM, batched over z (r4-proven config).
// Block 256 thr = 4 waves (2x2). BK=64, triple-buffered LDS, depth-2
// counted-vmcnt pipeline (vmcnt(4) keeps next tile's 4 loads in flight
// across the barrier). Used for the attention GEMMs (QK^T, PV).
// ---------------------------------------------------------------------------
__device__ __forceinline__ void stage64(
    const unsigned short* __restrict__ g, int row0, int k0, int ld,
    char* region, int wid, int lane)
{
    int c = wid * 64 + lane;                 // chunk 0..255
    int row = c >> 2, p = c & 3;
    int kc = (p - (row >> 1)) & 3;
    g2l16(g + (long)(row0 + row) * ld + k0 + kc * 8,
          region + (wid * 64) * 16);         // wave-uniform base
}

__device__ __forceinline__ void stage_tile(
    const unsigned short* __restrict__ A, const unsigned short* __restrict__ B,
    int row0, int col0, int k0, int lda, int ldb,
    char* buf, int wid, int lane)
{
    stage64(A, row0, k0,      lda, buf,         wid, lane);
    stage64(A, row0, k0 + 32, lda, buf +  4096, wid, lane);
    stage64(B, col0, k0,      ldb, buf +  8192, wid, lane);
    stage64(B, col0, k0 + 32, ldb, buf + 12288, wid, lane);
    __builtin_amdgcn_sched_barrier(0);       // keep the 4 loads contiguous
}

__global__ __launch_bounds__(256, 3) void gemm64(
    const unsigned short* __restrict__ A, const unsigned short* __restrict__ B,
    const float* __restrict__ bias, void* __restrict__ Cv,
    int K, int lda, int ldb, int ldc,
    long sA, long sB, long sC, int relu, int out_bf16)
{
    __shared__ char smem[3][16384];          // per buf: A0|A1|B0|B1 (4KB each)
    A += (long)blockIdx.z * sA;
    B += (long)blockIdx.z * sB;
    const int t = threadIdx.x, lane = t & 63, wid = t >> 6;
    const int wm = wid >> 1, wn = wid & 1;
    const int r16 = lane & 15, quad = lane >> 4;
    const int row0 = blockIdx.y * 64, col0 = blockIdx.x * 64;

    f32x4 acc[2][2] = {};
    const int NT = K >> 6;                   // K is a multiple of 64 here

    stage_tile(A, B, row0, col0, 0, lda, ldb, smem[0], wid, lane);
    if (NT > 1)
        stage_tile(A, B, row0, col0, 64, lda, ldb, smem[1], wid, lane);

    int cur = 0, sb = 2;
    for (int kt = 0; kt < NT; ++kt) {
        if (kt + 1 < NT) asm volatile("s_waitcnt vmcnt(4)" ::: "memory");
        else             asm volatile("s_waitcnt vmcnt(0) lgkmcnt(0)" ::: "memory");
        __builtin_amdgcn_s_barrier();
        if (kt + 2 < NT) {
            stage_tile(A, B, row0, col0, (kt + 2) * 64, lda, ldb,
                       smem[sb], wid, lane);
            sb = (sb == 2) ? 0 : sb + 1;
        }
        const char* cb = smem[cur];
        cur = (cur == 2) ? 0 : cur + 1;
        #pragma unroll
        for (int h = 0; h < 2; ++h) {
            bf16x8 af[2], bfv[2];
            #pragma unroll
            for (int rt = 0; rt < 2; ++rt) {
                int row = wm * 32 + rt * 16 + r16;
                int p = (quad + (row >> 1)) & 3;
                af[rt] = *reinterpret_cast<const bf16x8*>(
                    cb + h * 4096 + row * 64 + p * 16);
            }
            #pragma unroll
            for (int ct = 0; ct < 2; ++ct) {
                int col = wn * 32 + ct * 16 + r16;
                int p = (quad + (col >> 1)) & 3;
                bfv[ct] = *reinterpret_cast<const bf16x8*>(
                    cb + 8192 + h * 4096 + col * 64 + p * 16);
            }
            #pragma unroll
            for (int rt = 0; rt < 2; ++rt)
                #pragma unroll
                for (int ct = 0; ct < 2; ++ct)
                    acc[rt][ct] = __builtin_amdgcn_mfma_f32_16x16x32_bf16(
                        af[rt], bfv[ct], acc[rt][ct], 0, 0, 0);
        }
    }

    float* Cf = (float*)Cv;
    unsigned short* Cb = (unsigned short*)Cv;
    const long zoff = (long)blockIdx.z * sC;
    #pragma unroll
    for (int rt = 0; rt < 2; ++rt) {
        #pragma unroll
        for (int ct = 0; ct < 2; ++ct) {
            f32x4 v = acc[rt][ct];
            int col = col0 + wn * 32 + ct * 16 + r16;
            float bi = bias ? bias[col] : 0.f;
            #pragma unroll
            for (int i = 0; i < 4; ++i) {
                v[i] += bi;
                if (relu) v[i] = fmaxf(v[i], 0.f);
            }
            int rbase = row0 + wm * 32 + rt * 16 + quad * 4;
            if (out_bf16) {
                #pragma unroll
                for (int i = 0; i < 4; ++i)
                    Cb[zoff + (long)(rbase + i) * ldc + col] = f2b(v[i]);
            } else {
                #pragma unroll
                for (int i = 0; i < 4; ++i)
                    Cf[zoff + (long)(rbase + i) * ldc + col] = v[i];
            }
        }
    }
}

// ---------------------------------------------------------------------------
// gemm64w: 64x64-tile GEMM with FP32 B-operand (host weights) consumed
// directly — no separate convert pass. B is staged fp32 via the SAME async
// global_load_lds pipeline (6 loads/tile -> vmcnt(6)); fp32->bf16 conversion
// happens at LDS->fragment read time (2x ds_read_b128 + 4x v_cvt_pk_bf16_f32
// per fragment). B-tile LDS rows are 128B (8 chunks of 16B = 4 fp32), chunk
// kc stored at position (kc+row)&7 -> fragment reads are 2-way-conflict
// (free, m136). LDS: A0|A1 4KB + B0|B1 8KB = 24KB/buf x 3 = 72KB.
// Same depth-2 counted-vmcnt schedule as gemm64 (r4-proven).
// ---------------------------------------------------------------------------
__device__ __forceinline__ void stage32w(
    const float* __restrict__ g, int col0, int k0, int ld,
    char* region, int tid)
{
    int wid = tid >> 6;
    int row = tid >> 3, p = tid & 7;         // chunks 0..255: rows 0..31
    int kc = (p - row) & 7;
    g2l16(g + (long)(col0 + row) * ld + k0 + kc * 4,
          region + wid * 1024);
    int c2 = tid + 256;                      // chunks 256..511: rows 32..63
    int row2 = c2 >> 3, p2 = c2 & 7;
    int kc2 = (p2 - row2) & 7;
    g2l16(g + (long)(col0 + row2) * ld + k0 + kc2 * 4,
          region + 4096 + wid * 1024);
}

__device__ __forceinline__ void stage_tile_w(
    const unsigned short* __restrict__ A, const float* __restrict__ B,
    int row0, int col0, int k0, int lda, int ldb,
    char* buf, int wid, int lane, int tid)
{
    stage64(A, row0, k0,      lda, buf,        wid, lane);
    stage64(A, row0, k0 + 32, lda, buf + 4096, wid, lane);
    stage32w(B, col0, k0,      ldb, buf +  8192, tid);
    stage32w(B, col0, k0 + 32, ldb, buf + 16384, tid);
    __builtin_amdgcn_sched_barrier(0);       // keep the 6 loads contiguous
}

__global__ __launch_bounds__(256, 2) void gemm64w(
    const unsigned short* __restrict__ A, const float* __restrict__ B,
    const float* __restrict__ bias, void* __restrict__ Cv,
    int K, int lda, int ldb, int ldc, int relu, int out_bf16,
    unsigned short* __restrict__ vt, int dv2)
{
    __shared__ char smem[3][24576];          // A0|A1 (4KB) | B0|B1 (8KB)
    const int t = threadIdx.x, lane = t & 63, wid = t >> 6;
    const int wm = wid >> 1, wn = wid & 1;
    const int r16 = lane & 15, quad = lane >> 4;
    const int row0 = blockIdx.y * 64, col0 = blockIdx.x * 64;

    f32x4 acc[2][2] = {};
    const int NT = K >> 6;                   // K in {768,1536,2048}

    stage_tile_w(A, B, row0, col0, 0, lda, ldb, smem[0], wid, lane, t);
    if (NT > 1)
        stage_tile_w(A, B, row0, col0, 64, lda, ldb, smem[1], wid, lane, t);

    int cur = 0, sb = 2;
    for (int kt = 0; kt < NT; ++kt) {
        // 6 loads/tile; depth-2: keep next tile's 6 in flight
        if (kt + 1 < NT) asm volatile("s_waitcnt vmcnt(6)" ::: "memory");
        else             asm volatile("s_waitcnt vmcnt(0) lgkmcnt(0)" ::: "memory");
        __builtin_amdgcn_s_barrier();
        if (kt + 2 < NT) {
            stage_tile_w(A, B, row0, col0, (kt + 2) * 64, lda, ldb,
                         smem[sb], wid, lane, t);
            sb = (sb == 2) ? 0 : sb + 1;
        }
        const char* cb = smem[cur];
        cur = (cur == 2) ? 0 : cur + 1;
        #pragma unroll
        for (int h = 0; h < 2; ++h) {
            bf16x8 af[2], bfv[2];
            #pragma unroll
            for (int rt = 0; rt < 2; ++rt) {
                int row = wm * 32 + rt * 16 + r16;
                int p = (quad + (row >> 1)) & 3;
                af[rt] = *reinterpret_cast<const bf16x8*>(
                    cb + h * 4096 + row * 64 + p * 16);
            }
            #pragma unroll
            for (int ct = 0; ct < 2; ++ct) {
                int brow = wn * 32 + ct * 16 + r16;
                const char* bb = cb + 8192 + h * 8192;
                int p0 = ((quad << 1) + brow) & 7;
                int p1 = ((quad << 1) + 1 + brow) & 7;
                f32x4 u0 = *reinterpret_cast<const f32x4*>(bb + brow * 128 + p0 * 16);
                f32x4 u1 = *reinterpret_cast<const f32x4*>(bb + brow * 128 + p1 * 16);
                union { bf16x8 v; unsigned int u[4]; } pk;
                pk.u[0] = cvt2(u0[0], u0[1]);
                pk.u[1] = cvt2(u0[2], u0[3]);
                pk.u[2] = cvt2(u1[0], u1[1]);
                pk.u[3] = cvt2(u1[2], u1[3]);
                bfv[ct] = pk.v;
            }
            #pragma unroll
            for (int rt = 0; rt < 2; ++rt)
                #pragma unroll
                for (int ct = 0; ct < 2; ++ct)
                    acc[rt][ct] = __builtin_amdgcn_mfma_f32_16x16x32_bf16(
                        af[rt], bfv[ct], acc[rt][ct], 0, 0, 0);
        }
    }

    float* Cf = (float*)Cv;
    unsigned short* Cb = (unsigned short*)Cv;
    const int vwrite = (vt != nullptr) && (col0 >= dv2);
    #pragma unroll
    for (int rt = 0; rt < 2; ++rt) {
        #pragma unroll
        for (int ct = 0; ct < 2; ++ct) {
            f32x4 v = acc[rt][ct];
            int col = col0 + wn * 32 + ct * 16 + r16;
            float bi = bias ? bias[col] : 0.f;
            #pragma unroll
            for (int i = 0; i < 4; ++i) {
                v[i] += bi;
                if (relu) v[i] = fmaxf(v[i], 0.f);
            }
            int rbase = row0 + wm * 32 + rt * 16 + quad * 4;
            if (vwrite) {
                ushort4 p;
                p.x = f2b(v[0]); p.y = f2b(v[1]); p.z = f2b(v[2]); p.w = f2b(v[3]);
                *reinterpret_cast<ushort4*>(vt + (long)(col - dv2) * NTOK + rbase) = p;
            } else if (out_bf16) {
                #pragma unroll
                for (int i = 0; i < 4; ++i)
                    Cb[(long)(rbase + i) * ldc + col] = f2b(v[i]);
            } else {
                #pragma unroll
                for (int i = 0; i < 4; ++i)
                    Cf[(long)(rbase + i) * ldc + col] = v[i];
            }
        }
    }
}

// ---------------------------------------------------------------------------
// Softmax over rows of length 384 (one wave per row); fp32 in, bf16 out.
// ---------------------------------------------------------------------------
__global__ __launch_bounds__(64) void softmax_rows(
    const float* __restrict__ S, unsigned short* __restrict__ P, float scale)
{
    const float* p = S + (long)blockIdx.x * NTOK;
    unsigned short* q = P + (long)blockIdx.x * NTOK;
    const int t = threadIdx.x;
    float vals[6];
    float vmax = -1e30f;
    #pragma unroll
    for (int i = 0; i < 6; ++i) {
        vals[i] = p[t + i * 64] * scale;
        vmax = fmaxf(vmax, vals[i]);
    }
    for (int off = 32; off; off >>= 1) vmax = fmaxf(vmax, __shfl_down(vmax, off));
    vmax = __shfl(vmax, 0);
    float sum = 0.f;
    #pragma unroll
    for (int i = 0; i < 6; ++i) { vals[i] = __expf(vals[i] - vmax); sum += vals[i]; }
    for (int off = 32; off; off >>= 1) sum += __shfl_down(sum, off);
    sum = __shfl(sum, 0);
    float inv = 1.f / sum;
    #pragma unroll
    for (int i = 0; i < 6; ++i) q[t + i * 64] = f2b(vals[i] * inv);
}

// ---------------------------------------------------------------------------
// x = LayerNorm(x + gb + y) * s + b  (fp32) + bf16 copy xb. gb is the gemm
// output bias (folded here). Row values cached in registers.
// ---------------------------------------------------------------------------
__global__ __launch_bounds__(256) void add_ln(
    float* __restrict__ x, unsigned short* __restrict__ xb,
    const float* __restrict__ y,
    const float* __restrict__ gb,
    const float* __restrict__ s, const float* __restrict__ b, int d)
{
    float* xr = x + (long)blockIdx.x * d;
    unsigned short* xbr = xb + (long)blockIdx.x * d;
    const float* yr = y + (long)blockIdx.x * d;
    const int t = threadIdx.x;
    float vv[6];                             // d/256 <= 6 (d in {768,1536})
    float s1 = 0.f, s2 = 0.f;
    #pragma unroll
    for (int j = 0; j < 6; ++j) {
        int i = t + j * 256;
        if (j * 256 < d) {
            float v = xr[i] + gb[i] + yr[i];
            vv[j] = v;
            s1 += v; s2 += v * v;
        }
    }
    for (int off = 32; off; off >>= 1) { s1 += __shfl_down(s1, off); s2 += __shfl_down(s2, off); }
    __shared__ float r1[4], r2[4];
    int w = t >> 6;
    if ((t & 63) == 0) { r1[w] = s1; r2[w] = s2; }
    __syncthreads();
    if (t == 0) {
        float a = 0.f, c = 0.f;
        for (int i = 0; i < 4; ++i) { a += r1[i]; c += r2[i]; }
        r1[0] = a; r2[0] = c;
    }
    __syncthreads();
    float mean = r1[0] / d;
    float var = r2[0] / d - mean * mean;
    float rstd = rsqrtf(var + 1e-5f);
    #pragma unroll
    for (int j = 0; j < 6; ++j) {
        int i = t + j * 256;
        if (j * 256 < d) {
            float v = (vv[j] - mean) * rstd * s[i] + b[i];
            xr[i] = v;
            xbr[i] = f2b(v);
        }
    }
}

// ---------------------------------------------------------------------------
// init / concat (write fp32 + bf16 copies)
// ---------------------------------------------------------------------------
__global__ void initx_k(const float* __restrict__ src, float* __restrict__ dst,
                        unsigned short* __restrict__ dstb, int n)
{
    int i = blockIdx.x * blockDim.x + threadIdx.x;
    if (i < n) { float v = src[i]; dst[i] = v; dstb[i] = f2b(v); }
}

__global__ void concat_k(const float* __restrict__ te, const float* __restrict__ ve,
                         float* __restrict__ all, unsigned short* __restrict__ allb)
{
    int i = blockIdx.x * blockDim.x + threadIdx.x;
    if (i >= NTOK * 1536) return;
    int r = i / 1536, c = i % 1536;
    float v = (c < 768) ? te[r * 768 + c] : ve[r * 768 + (c - 768)];
    all[i] = v;
    allb[i] = f2b(v);
}

// ---------------------------------------------------------------------------
// head kernels (fp32)
// ---------------------------------------------------------------------------
__global__ __launch_bounds__(256) void head_ac(
    const float* __restrict__ all, const float* __restrict__ lin_w,
    const float* __restrict__ lin_b, float* __restrict__ a, float* __restrict__ c)
{
    const int i = blockIdx.x, t = threadIdx.x;
    const float* xr = all + (long)i * 1536;
    float s0 = 0.f, s1 = 0.f, s2 = 0.f, s3 = 0.f;
    for (int e = t; e < 1536; e += 256) {
        float v = xr[e];
        s0 += v * lin_w[e];
        s1 += v * lin_w[3072 + e];
        s2 += v * lin_w[1536 + e];
        s3 += v * lin_w[4608 + e];
    }
    for (int off = 32; off; off >>= 1) {
        s0 += __shfl_down(s0, off); s1 += __shfl_down(s1, off);
        s2 += __shfl_down(s2, off); s3 += __shfl_down(s3, off);
    }
    __shared__ float r[4][4];
    int w = t >> 6;
    if ((t & 63) == 0) { r[0][w] = s0; r[1][w] = s1; r[2][w] = s2; r[3][w] = s3; }
    __syncthreads();
    if (t == 0) {
        float t0 = 0.f, t1 = 0.f, t2 = 0.f, t3 = 0.f;
        for (int k = 0; k < 4; ++k) { t0 += r[0][k]; t1 += r[1][k]; t2 += r[2][k]; t3 += r[3][k]; }
        a[i * 2 + 0] = t0 + lin_b[0];
        a[i * 2 + 1] = t1 + lin_b[1];
        c[i * 2 + 0] = t2;
        c[i * 2 + 1] = t3;
    }
}

__global__ __launch_bounds__(384) void head_probs(
    const float* __restrict__ a, const float* __restrict__ c,
    const int* __restrict__ gt, float* __restrict__ probs,
    float* __restrict__ rowsum, float* __restrict__ rowcell)
{
    const int i = blockIdx.x, j = threadIdx.x;
    float l0 = a[i * 2 + 0] + c[j * 2 + 0];
    float l1 = a[i * 2 + 1] + c[j * 2 + 1];
    float m = fmaxf(l0, l1);
    float e0 = __expf(l0 - m), e1 = __expf(l1 - m);
    float inv = 1.f / (e0 + e1);
    float p0 = e0 * inv, p1 = e1 * inv;
    long base = ((long)i * NTOK + j) * 2;
    probs[base] = p0;
    probs[base + 1] = p1;
    float m2 = fmaxf(p0, p1);
    float z = m2 + __logf(__expf(p0 - m2) + __expf(p1 - m2));
    int g = gt[i * NTOK + j];
    float cell = z - (g ? p1 : p0);
    float cs = cell, ps = p1;
    for (int off = 32; off; off >>= 1) { cs += __shfl_down(cs, off); ps += __shfl_down(ps, off); }
    __shared__ float rc[6], rs[6];
    int w = j >> 6;
    if ((j & 63) == 0) { rc[w] = cs; rs[w] = ps; }
    __syncthreads();
    if (j == 0) {
        float csum = 0.f, psum = 0.f;
        for (int k = 0; k < 6; ++k) { csum += rc[k]; psum += rs[k]; }
        rowcell[i] = csum * (1.f / NTOK);
        rowsum[i] = psum;
    }
}

__global__ __launch_bounds__(64) void colsum_k(const float* __restrict__ probs,
                                               float* __restrict__ colsum)
{
    const int j = blockIdx.x, t = threadIdx.x;
    float s = 0.f;
    for (int i = t; i < NTOK; i += 64)
        s += probs[((long)i * NTOK + j) * 2 + 1];
    for (int off = 32; off; off >>= 1) s += __shfl_down(s, off);
    if (t == 0) colsum[j] = s;
}

__global__ __launch_bounds__(384) void finalize_k(
    const float* __restrict__ rowcell, const float* __restrict__ rowsum,
    const float* __restrict__ colsum, float* __restrict__ out)
{
    const int t = threadIdx.x;
    float cls = rowcell[t];
    float ee = (t < NTOK - 1) ? fabsf(rowsum[t] + colsum[t] - 1.f) : 0.f;
    for (int off = 32; off; off >>= 1) { cls += __shfl_down(cls, off); ee += __shfl_down(ee, off); }
    __shared__ float rc[6], re[6];
    int w = t >> 6;
    if ((t & 63) == 0) { rc[w] = cls; re[w] = ee; }
    __syncthreads();
    if (t == 0) {
        float a = 0.f, b = 0.f;
        for (int k = 0; k < 6; ++k) { a += rc[k]; b += re[k]; }
        out[NTOK * NTOK * 2 + 0] = a;
        out[NTOK * NTOK * 2 + 1] = b;
    }
}

// ---------------------------------------------------------------------------
// host-side encoder driver: gemm64w (fp32 weights, convert-on-read) for
// weight gemms; gemm64 (bf16) for attention gemms.
// ---------------------------------------------------------------------------
static void run_encoder(float* x, unsigned short* xb, int d,
                        const float* wq, const float* wo,
                        const float* w1, const float* w2,
                        const float* qkv_b, const float* out_b,
                        const float* ln1_s, const float* ln1_b,
                        const float* ff1_b, const float* ff2_b,
                        const float* ln2_s, const float* ln2_b,
                        unsigned short* qkvb, float* sc, unsigned short* attnb,
                        unsigned short* vtb, unsigned short* ob,
                        unsigned short* t1b, float* t2,
                        hipStream_t stream)
{
    const int dq = 3 * d;
    const int hd = d / HEADS;
    const float scale = 1.0f / sqrtf((float)hd);
    for (int l = 0; l < 2; ++l) {
        // qkv = x @ Wqkv^T + b (bf16; V block written transposed to vtb)
        gemm64w<<<dim3(dq / 64, 6), 256, 0, stream>>>(
            xb, wq + (long)l * dq * d, qkv_b + l * dq, qkvb,
            d, d, d, dq, 0, 1, vtb, 2 * d);
        // scores = Q @ K^T (fp32), batched over heads
        gemm64<<<dim3(6, 6, HEADS), 256, 0, stream>>>(
            qkvb, qkvb + d, nullptr, sc,
            hd, dq, dq, NTOK, (long)hd, (long)hd, (long)NTOK * NTOK, 0, 0);
        softmax_rows<<<HEADS * NTOK, 64, 0, stream>>>(sc, attnb, scale);
        // o = attn @ V^T (bf16), batched over heads
        gemm64<<<dim3(hd / 64, 6, HEADS), 256, 0, stream>>>(
            attnb, vtb, nullptr, ob,
            NTOK, NTOK, NTOK, d, (long)NTOK * NTOK, (long)hd * NTOK, (long)hd,
            0, 1);
        // out-proj (fp32) + LN (bias folded into add_ln)
        gemm64w<<<dim3(d / 64, 6), 256, 0, stream>>>(
            ob, wo + (long)l * d * d, nullptr, t2,
            d, d, d, d, 0, 0, nullptr, 0);
        add_ln<<<NTOK, 256, 0, stream>>>(x, xb, t2,
                                         out_b + l * d, ln1_s + l * d, ln1_b + l * d, d);
        // ff1 (relu, bf16)
        gemm64w<<<dim3(2048 / 64, 6), 256, 0, stream>>>(
            xb, w1 + (long)l * 2048 * d, ff1_b + l * 2048, t1b,
            d, d, d, 2048, 1, 1, nullptr, 0);
        // ff2 (fp32) + LN (bias folded into add_ln)
        gemm64w<<<dim3(d / 64, 6), 256, 0, stream>>>(
            t1b, w2 + (long)l * d * 2048, nullptr, t2,
            2048, 2048, 2048, d, 0, 0, nullptr, 0);
        add_ln<<<NTOK, 256, 0, stream>>>(x, xb, t2,
                                         ff2_b + l * d, ln2_s + l * d, ln2_b + l * d, d);
    }
}

extern "C" void kernel_launch(void* const* d_in, const int* in_sizes, int n_in,
                              void* d_out, int out_size, void* d_ws, size_t ws_size,
                              hipStream_t stream)
{
    const float* text_emb   = (const float*)d_in[0];
    const float* vision_emb = (const float*)d_in[1];
    const int*   gt         = (const int*)  d_in[2];
    const float* t_qkv_w = (const float*)d_in[3];
    const float* t_qkv_b = (const float*)d_in[4];
    const float* t_out_w = (const float*)d_in[5];
    const float* t_out_b = (const float*)d_in[6];
    const float* t_ln1_s = (const float*)d_in[7];
    const float* t_ln1_b = (const float*)d_in[8];
    const float* t_ff1_w = (const float*)d_in[9];
    const float* t_ff1_b = (const float*)d_in[10];
    const float* t_ff2_w = (const float*)d_in[11];
    const float* t_ff2_b = (const float*)d_in[12];
    const float* t_ln2_s = (const float*)d_in[13];
    const float* t_ln2_b = (const float*)d_in[14];
    const float* c_qkv_w = (const float*)d_in[15];
    const float* c_qkv_b = (const float*)d_in[16];
    const float* c_out_w = (const float*)d_in[17];
    const float* c_out_b = (const float*)d_in[18];
    const float* c_ln1_s = (const float*)d_in[19];
    const float* c_ln1_b = (const float*)d_in[20];
    const float* c_ff1_w = (const float*)d_in[21];
    const float* c_ff1_b = (const float*)d_in[22];
    const float* c_ff2_w = (const float*)d_in[23];
    const float* c_ff2_b = (const float*)d_in[24];
    const float* c_ln2_s = (const float*)d_in[25];
    const float* c_ln2_b = (const float*)d_in[26];
    const float* lin_w   = (const float*)d_in[27];
    const float* lin_b   = (const float*)d_in[28];
    float* out = (float*)d_out;

    // ---- workspace layout ----
    float* ws = (float*)d_ws;
    float* xt      = ws;                 // 384*768
    float* all     = xt + 294912;        // 384*1536
    float* t2      = all + 589824;       // 384*1536 (max)
    float* sc      = t2 + 589824;        // 4*384*384 fp32
    float* abuf    = sc + 589824;
    float* cbuf    = abuf + 768;
    float* rowsum  = cbuf + 768;
    float* rowcell = rowsum + 384;
    float* colsum  = rowcell + 384;      // fp32 total 2067072
    unsigned short* ub = (unsigned short*)(ws + 2067072);
    unsigned short* xtb   = ub;                  // 294912
    unsigned short* allb  = xtb + 294912;        // 589824
    unsigned short* qkvb  = allb + 589824;       // 384*4608
    unsigned short* attnb = qkvb + 1769472;      // 4*384*384
    unsigned short* vtb   = attnb + 589824;      // 1536*384 (max)
    unsigned short* ob    = vtb + 589824;        // 589824
    unsigned short* t1b   = ob + 589824;         // 384*2048

    // ---- text encoder (d = 768) ----
    initx_k<<<(294912 + 255) / 256, 256, 0, stream>>>(text_emb, xt, xtb, 294912);
    run_encoder(xt, xtb, 768,
                t_qkv_w, t_out_w, t_ff1_w, t_ff2_w,
                t_qkv_b, t_out_b, t_ln1_s, t_ln1_b,
                t_ff1_b, t_ff2_b, t_ln2_s, t_ln2_b,
                qkvb, sc, attnb, vtb, ob, t1b, t2, stream);

    // ---- concat -> combined encoder (d = 1536) ----
    concat_k<<<(589824 + 255) / 256, 256, 0, stream>>>(xt, vision_emb, all, allb);
    run_encoder(all, allb, 1536,
                c_qkv_w, c_out_w, c_ff1_w, c_ff2_w,
                c_qkv_b, c_out_b, c_ln1_s, c_ln1_b,
                c_ff1_b, c_ff2_b, c_ln2_s, c_ln2_b,
                qkvb, sc, attnb, vtb, ob, t1b, t2, stream);

    // ---- head ----
    head_ac<<<NTOK, 256, 0, stream>>>(all, lin_w, lin_b, abuf, cbuf);
    head_probs<<<NTOK, 384, 0, stream>>>(abuf, cbuf, gt, out, rowsum, rowcell);
    colsum_k<<<NTOK, 64, 0, stream>>>(out, colsum);
    finalize_k<<<1, 384, 0, stream>>>(rowcell, rowsum, colsum, out);
}

// Round 11
// 506.602 us; speedup vs baseline: 1.1997x; 1.0874x over previous
//
#include <hip/hip_runtime.h>
#include <hip/hip_bf16.h>
#include <math.h>

#define NTOK 384
#define HEADS 4

typedef __attribute__((ext_vector_type(8))) short bf16x8;
typedef __attribute__((ext_vector_type(4))) float f32x4;

__device__ __forceinline__ unsigned short f2b(float f) {
    union { float f; unsigned int u; } v; v.f = f;
    unsigned int r = (v.u + 0x7fff + ((v.u >> 16) & 1)) >> 16;  // RNE
    return (unsigned short)r;
}

// async 16B global -> LDS (wave-uniform LDS base; HW adds lane*16)
__device__ __forceinline__ void g2l16(const void* g, void* l) {
    __builtin_amdgcn_global_load_lds(
        (const __attribute__((address_space(1))) unsigned int*)g,
        (__attribute__((address_space(3))) unsigned int*)l, 16, 0, 0);
}

// ---------------------------------------------------------------------------
// 64x64-tile MFMA bf16 GEMM, batched over z. C = A@B^T + bias, opt relu,
// fp32/bf16 out, optional transposed-V epilogue for col0 >= dv2.
// Block 256 thr = 4 waves (2x2, 32x32 each). BK=64, QUAD-buffered LDS with a
// DEPTH-3 counted-vmcnt pipeline: s_barrier + s_waitcnt vmcnt(8) keeps TWO
// tiles' global_load_lds in flight across the barrier (~2 compute phases of
// cover vs ~900cy first-touch HBM latency; depth-2 covered only ~1 phase).
// These GEMMs run at ~1 block/CU so nothing else hides latency.
// Safety (r5-verified): stage(kt+3) after barrier(kt) overwrites
// smem[(kt-1)&3], whose last reader compute(kt-1) finished before
// barrier(kt); at the wait point tiles kt..kt+2 are in flight (12 loads),
// vmcnt(8) retires exactly tile kt's 4.
// ---------------------------------------------------------------------------
__device__ __forceinline__ void stage64(
    const unsigned short* __restrict__ g, int row0, int k0, int ld,
    char* region, int wid, int lane)
{
    int c = wid * 64 + lane;                 // chunk 0..255
    int row = c >> 2, p = c & 3;
    int kc = (p - (row >> 1)) & 3;
    g2l16(g + (long)(row0 + row) * ld + k0 + kc * 8,
          region + (wid * 64) * 16);         // wave-uniform base
}

__device__ __forceinline__ void stage_tile(
    const unsigned short* __restrict__ A, const unsigned short* __restrict__ B,
    int row0, int col0, int k0, int lda, int ldb,
    char* buf, int wid, int lane)
{
    stage64(A, row0, k0,      lda, buf,         wid, lane);
    stage64(A, row0, k0 + 32, lda, buf +  4096, wid, lane);
    stage64(B, col0, k0,      ldb, buf +  8192, wid, lane);
    stage64(B, col0, k0 + 32, ldb, buf + 12288, wid, lane);
    __builtin_amdgcn_sched_barrier(0);       // keep the 4 loads contiguous
}

__global__ __launch_bounds__(256, 2) void gemm64(
    const unsigned short* __restrict__ A, const unsigned short* __restrict__ B,
    const float* __restrict__ bias, void* __restrict__ Cv,
    int K, int lda, int ldb, int ldc,
    long sA, long sB, long sC, int relu, int out_bf16,
    unsigned short* __restrict__ vt, int dv2)
{
    __shared__ char smem[4][16384];          // per buf: A0|A1|B0|B1 (4KB each)
    A += (long)blockIdx.z * sA;
    B += (long)blockIdx.z * sB;
    const int t = threadIdx.x, lane = t & 63, wid = t >> 6;
    const int wm = wid >> 1, wn = wid & 1;
    const int r16 = lane & 15, quad = lane >> 4;
    const int row0 = blockIdx.y * 64, col0 = blockIdx.x * 64;

    f32x4 acc[2][2] = {};
    const int NT = K >> 6;                   // K is a multiple of 64 here

    stage_tile(A, B, row0, col0, 0, lda, ldb, smem[0], wid, lane);
    if (NT > 1) stage_tile(A, B, row0, col0,  64, lda, ldb, smem[1], wid, lane);
    if (NT > 2) stage_tile(A, B, row0, col0, 128, lda, ldb, smem[2], wid, lane);

    for (int kt = 0; kt < NT; ++kt) {
        const int rem = NT - 1 - kt;         // tiles after this one
        if (rem >= 2)      asm volatile("s_waitcnt vmcnt(8)" ::: "memory");
        else if (rem == 1) asm volatile("s_waitcnt vmcnt(4)" ::: "memory");
        else               asm volatile("s_waitcnt vmcnt(0) lgkmcnt(0)" ::: "memory");
        __builtin_amdgcn_s_barrier();
        if (kt + 3 < NT)
            stage_tile(A, B, row0, col0, (kt + 3) * 64, lda, ldb,
                       smem[(kt + 3) & 3], wid, lane);
        const char* cb = smem[kt & 3];
        #pragma unroll
        for (int h = 0; h < 2; ++h) {
            bf16x8 af[2], bfv[2];
            #pragma unroll
            for (int rt = 0; rt < 2; ++rt) {
                int row = wm * 32 + rt * 16 + r16;
                int p = (quad + (row >> 1)) & 3;
                af[rt] = *reinterpret_cast<const bf16x8*>(
                    cb + h * 4096 + row * 64 + p * 16);
            }
            #pragma unroll
            for (int ct = 0; ct < 2; ++ct) {
                int col = wn * 32 + ct * 16 + r16;
                int p = (quad + (col >> 1)) & 3;
                bfv[ct] = *reinterpret_cast<const bf16x8*>(
                    cb + 8192 + h * 4096 + col * 64 + p * 16);
            }
            #pragma unroll
            for (int rt = 0; rt < 2; ++rt)
                #pragma unroll
                for (int ct = 0; ct < 2; ++ct)
                    acc[rt][ct] = __builtin_amdgcn_mfma_f32_16x16x32_bf16(
                        af[rt], bfv[ct], acc[rt][ct], 0, 0, 0);
        }
    }

    float* Cf = (float*)Cv;
    unsigned short* Cb = (unsigned short*)Cv;
    const long zoff = (long)blockIdx.z * sC;
    const int vwrite = (vt != nullptr) && (col0 >= dv2);
    #pragma unroll
    for (int rt = 0; rt < 2; ++rt) {
        #pragma unroll
        for (int ct = 0; ct < 2; ++ct) {
            f32x4 v = acc[rt][ct];
            int col = col0 + wn * 32 + ct * 16 + r16;
            float bi = bias ? bias[col] : 0.f;
            #pragma unroll
            for (int i = 0; i < 4; ++i) {
                v[i] += bi;
                if (relu) v[i] = fmaxf(v[i], 0.f);
            }
            int rbase = row0 + wm * 32 + rt * 16 + quad * 4;
            if (vwrite) {
                ushort4 p;
                p.x = f2b(v[0]); p.y = f2b(v[1]); p.z = f2b(v[2]); p.w = f2b(v[3]);
                *reinterpret_cast<ushort4*>(vt + (long)(col - dv2) * NTOK + rbase) = p;
            } else if (out_bf16) {
                #pragma unroll
                for (int i = 0; i < 4; ++i)
                    Cb[zoff + (long)(rbase + i) * ldc + col] = f2b(v[i]);
            } else {
                #pragma unroll
                for (int i = 0; i < 4; ++i)
                    Cf[zoff + (long)(rbase + i) * ldc + col] = v[i];
            }
        }
    }
}

// ---------------------------------------------------------------------------
// Fused fp32 -> bf16 conversion of all 8 weight tensors. 16 elems/thread;
// NON-TEMPORAL loads (via ext_vector f32x4 — HIP float4 is a class type the
// builtin rejects): the fp32 sources are dead after this pass, so keep them
// out of L3 — leaves the 85MB bf16 destination resident for the GEMMs.
// ---------------------------------------------------------------------------
#define WO0 0u
#define WO1 3538944u
#define WO2 4718592u
#define WO3 7864320u
#define WO4 11010048u
#define WO5 25165824u
#define WO6 29884416u
#define WO7 36175872u
#define WTOT 42467328u

__global__ __launch_bounds__(256) void convert_weights(
    const float* __restrict__ s0, const float* __restrict__ s1,
    const float* __restrict__ s2, const float* __restrict__ s3,
    const float* __restrict__ s4, const float* __restrict__ s5,
    const float* __restrict__ s6, const float* __restrict__ s7,
    unsigned short* __restrict__ dst)
{
    unsigned int e = (blockIdx.x * 256u + threadIdx.x) * 16u;
    if (e >= WTOT) return;
    const float* src; unsigned int local;
    if      (e < WO1) { src = s0; local = e - WO0; }
    else if (e < WO2) { src = s1; local = e - WO1; }
    else if (e < WO3) { src = s2; local = e - WO2; }
    else if (e < WO4) { src = s3; local = e - WO3; }
    else if (e < WO5) { src = s4; local = e - WO4; }
    else if (e < WO6) { src = s5; local = e - WO5; }
    else if (e < WO7) { src = s6; local = e - WO6; }
    else              { src = s7; local = e - WO7; }
    f32x4 v0 = __builtin_nontemporal_load(reinterpret_cast<const f32x4*>(src + local));
    f32x4 v1 = __builtin_nontemporal_load(reinterpret_cast<const f32x4*>(src + local + 4));
    f32x4 v2 = __builtin_nontemporal_load(reinterpret_cast<const f32x4*>(src + local + 8));
    f32x4 v3 = __builtin_nontemporal_load(reinterpret_cast<const f32x4*>(src + local + 12));
    uint4 o0, o1;
    o0.x = (unsigned)f2b(v0[0]) | ((unsigned)f2b(v0[1]) << 16);
    o0.y = (unsigned)f2b(v0[2]) | ((unsigned)f2b(v0[3]) << 16);
    o0.z = (unsigned)f2b(v1[0]) | ((unsigned)f2b(v1[1]) << 16);
    o0.w = (unsigned)f2b(v1[2]) | ((unsigned)f2b(v1[3]) << 16);
    o1.x = (unsigned)f2b(v2[0]) | ((unsigned)f2b(v2[1]) << 16);
    o1.y = (unsigned)f2b(v2[2]) | ((unsigned)f2b(v2[3]) << 16);
    o1.z = (unsigned)f2b(v3[0]) | ((unsigned)f2b(v3[1]) << 16);
    o1.w = (unsigned)f2b(v3[2]) | ((unsigned)f2b(v3[3]) << 16);
    *reinterpret_cast<uint4*>(dst + e) = o0;
    *reinterpret_cast<uint4*>(dst + e + 8) = o1;
}

// ---------------------------------------------------------------------------
// Softmax over rows of length 384 (one wave per row); fp32 in, bf16 out.
// ---------------------------------------------------------------------------
__global__ __launch_bounds__(64) void softmax_rows(
    const float* __restrict__ S, unsigned short* __restrict__ P, float scale)
{
    const float* p = S + (long)blockIdx.x * NTOK;
    unsigned short* q = P + (long)blockIdx.x * NTOK;
    const int t = threadIdx.x;
    float vals[6];
    float vmax = -1e30f;
    #pragma unroll
    for (int i = 0; i < 6; ++i) {
        vals[i] = p[t + i * 64] * scale;
        vmax = fmaxf(vmax, vals[i]);
    }
    for (int off = 32; off; off >>= 1) vmax = fmaxf(vmax, __shfl_down(vmax, off));
    vmax = __shfl(vmax, 0);
    float sum = 0.f;
    #pragma unroll
    for (int i = 0; i < 6; ++i) { vals[i] = __expf(vals[i] - vmax); sum += vals[i]; }
    for (int off = 32; off; off >>= 1) sum += __shfl_down(sum, off);
    sum = __shfl(sum, 0);
    float inv = 1.f / sum;
    #pragma unroll
    for (int i = 0; i < 6; ++i) q[t + i * 64] = f2b(vals[i] * inv);
}

// ---------------------------------------------------------------------------
// x = LayerNorm(x + y) * s + b  (fp32), also writes bf16 copy xb.
// ---------------------------------------------------------------------------
__global__ __launch_bounds__(256) void add_ln(
    float* __restrict__ x, unsigned short* __restrict__ xb,
    const float* __restrict__ y,
    const float* __restrict__ s, const float* __restrict__ b, int d)
{
    float* xr = x + (long)blockIdx.x * d;
    unsigned short* xbr = xb + (long)blockIdx.x * d;
    const float* yr = y + (long)blockIdx.x * d;
    const int t = threadIdx.x;
    float s1 = 0.f, s2 = 0.f;
    for (int i = t; i < d; i += 256) {
        float v = xr[i] + yr[i];
        s1 += v; s2 += v * v;
    }
    for (int off = 32; off; off >>= 1) { s1 += __shfl_down(s1, off); s2 += __shfl_down(s2, off); }
    __shared__ float r1[4], r2[4];
    int w = t >> 6;
    if ((t & 63) == 0) { r1[w] = s1; r2[w] = s2; }
    __syncthreads();
    if (t == 0) {
        float a = 0.f, c = 0.f;
        for (int i = 0; i < 4; ++i) { a += r1[i]; c += r2[i]; }
        r1[0] = a; r2[0] = c;
    }
    __syncthreads();
    float mean = r1[0] / d;
    float var = r2[0] / d - mean * mean;
    float rstd = rsqrtf(var + 1e-5f);
    for (int i = t; i < d; i += 256) {
        float v = (xr[i] + yr[i] - mean) * rstd * s[i] + b[i];
        xr[i] = v;
        xbr[i] = f2b(v);
    }
}

// ---------------------------------------------------------------------------
// init / concat (write fp32 + bf16 copies)
// ---------------------------------------------------------------------------
__global__ void initx_k(const float* __restrict__ src, float* __restrict__ dst,
                        unsigned short* __restrict__ dstb, int n)
{
    int i = blockIdx.x * blockDim.x + threadIdx.x;
    if (i < n) { float v = src[i]; dst[i] = v; dstb[i] = f2b(v); }
}

__global__ void concat_k(const float* __restrict__ te, const float* __restrict__ ve,
                         float* __restrict__ all, unsigned short* __restrict__ allb)
{
    int i = blockIdx.x * blockDim.x + threadIdx.x;
    if (i >= NTOK * 1536) return;
    int r = i / 1536, c = i % 1536;
    float v = (c < 768) ? te[r * 768 + c] : ve[r * 768 + (c - 768)];
    all[i] = v;
    allb[i] = f2b(v);
}

// ---------------------------------------------------------------------------
// head kernels (fp32)
// ---------------------------------------------------------------------------
__global__ __launch_bounds__(256) void head_ac(
    const float* __restrict__ all, const float* __restrict__ lin_w,
    const float* __restrict__ lin_b, float* __restrict__ a, float* __restrict__ c)
{
    const int i = blockIdx.x, t = threadIdx.x;
    const float* xr = all + (long)i * 1536;
    float s0 = 0.f, s1 = 0.f, s2 = 0.f, s3 = 0.f;
    for (int e = t; e < 1536; e += 256) {
        float v = xr[e];
        s0 += v * lin_w[e];
        s1 += v * lin_w[3072 + e];
        s2 += v * lin_w[1536 + e];
        s3 += v * lin_w[4608 + e];
    }
    for (int off = 32; off; off >>= 1) {
        s0 += __shfl_down(s0, off); s1 += __shfl_down(s1, off);
        s2 += __shfl_down(s2, off); s3 += __shfl_down(s3, off);
    }
    __shared__ float r[4][4];
    int w = t >> 6;
    if ((t & 63) == 0) { r[0][w] = s0; r[1][w] = s1; r[2][w] = s2; r[3][w] = s3; }
    __syncthreads();
    if (t == 0) {
        float t0 = 0.f, t1 = 0.f, t2 = 0.f, t3 = 0.f;
        for (int k = 0; k < 4; ++k) { t0 += r[0][k]; t1 += r[1][k]; t2 += r[2][k]; t3 += r[3][k]; }
        a[i * 2 + 0] = t0 + lin_b[0];
        a[i * 2 + 1] = t1 + lin_b[1];
        c[i * 2 + 0] = t2;
        c[i * 2 + 1] = t3;
    }
}

__global__ __launch_bounds__(384) void head_probs(
    const float* __restrict__ a, const float* __restrict__ c,
    const int* __restrict__ gt, float* __restrict__ probs,
    float* __restrict__ rowsum, float* __restrict__ rowcell)
{
    const int i = blockIdx.x, j = threadIdx.x;
    float l0 = a[i * 2 + 0] + c[j * 2 + 0];
    float l1 = a[i * 2 + 1] + c[j * 2 + 1];
    float m = fmaxf(l0, l1);
    float e0 = __expf(l0 - m), e1 = __expf(l1 - m);
    float inv = 1.f / (e0 + e1);
    float p0 = e0 * inv, p1 = e1 * inv;
    long base = ((long)i * NTOK + j) * 2;
    probs[base] = p0;
    probs[base + 1] = p1;
    float m2 = fmaxf(p0, p1);
    float z = m2 + __logf(__expf(p0 - m2) + __expf(p1 - m2));
    int g = gt[i * NTOK + j];
    float cell = z - (g ? p1 : p0);
    float cs = cell, ps = p1;
    for (int off = 32; off; off >>= 1) { cs += __shfl_down(cs, off); ps += __shfl_down(ps, off); }
    __shared__ float rc[6], rs[6];
    int w = j >> 6;
    if ((j & 63) == 0) { rc[w] = cs; rs[w] = ps; }
    __syncthreads();
    if (j == 0) {
        float csum = 0.f, psum = 0.f;
        for (int k = 0; k < 6; ++k) { csum += rc[k]; psum += rs[k]; }
        rowcell[i] = csum * (1.f / NTOK);
        rowsum[i] = psum;
    }
}

__global__ __launch_bounds__(64) void colsum_k(const float* __restrict__ probs,
                                               float* __restrict__ colsum)
{
    const int j = blockIdx.x, t = threadIdx.x;
    float s = 0.f;
    for (int i = t; i < NTOK; i += 64)
        s += probs[((long)i * NTOK + j) * 2 + 1];
    for (int off = 32; off; off >>= 1) s += __shfl_down(s, off);
    if (t == 0) colsum[j] = s;
}

__global__ __launch_bounds__(384) void finalize_k(
    const float* __restrict__ rowcell, const float* __restrict__ rowsum,
    const float* __restrict__ colsum, float* __restrict__ out)
{
    const int t = threadIdx.x;
    float cls = rowcell[t];
    float ee = (t < NTOK - 1) ? fabsf(rowsum[t] + colsum[t] - 1.f) : 0.f;
    for (int off = 32; off; off >>= 1) { cls += __shfl_down(cls, off); ee += __shfl_down(ee, off); }
    __shared__ float rc[6], re[6];
    int w = t >> 6;
    if ((t & 63) == 0) { rc[w] = cls; re[w] = ee; }
    __syncthreads();
    if (t == 0) {
        float a = 0.f, b = 0.f;
        for (int k = 0; k < 6; ++k) { a += rc[k]; b += re[k]; }
        out[NTOK * NTOK * 2 + 0] = a;
        out[NTOK * NTOK * 2 + 1] = b;
    }
}

// ---------------------------------------------------------------------------
// host-side encoder driver (bf16 weights, 64-tile staged gemms)
// ---------------------------------------------------------------------------
static void run_encoder(float* x, unsigned short* xb, int d,
                        const unsigned short* wq, const unsigned short* wo,
                        const unsigned short* w1, const unsigned short* w2,
                        const float* qkv_b, const float* out_b,
                        const float* ln1_s, const float* ln1_b,
                        const float* ff1_b, const float* ff2_b,
                        const float* ln2_s, const float* ln2_b,
                        unsigned short* qkvb, float* sc, unsigned short* attnb,
                        unsigned short* vtb, unsigned short* ob,
                        unsigned short* t1b, float* t2,
                        hipStream_t stream)
{
    const int dq = 3 * d;
    const int hd = d / HEADS;
    const float scale = 1.0f / sqrtf((float)hd);
    for (int l = 0; l < 2; ++l) {
        // qkv = x @ Wqkv^T + b (bf16; V block written transposed to vtb)
        gemm64<<<dim3(dq / 64, 6), 256, 0, stream>>>(
            xb, wq + (long)l * dq * d, qkv_b + l * dq, qkvb,
            d, d, d, dq, 0, 0, 0, 0, 1, vtb, 2 * d);
        // scores = Q @ K^T (fp32), batched over heads
        gemm64<<<dim3(6, 6, HEADS), 256, 0, stream>>>(
            qkvb, qkvb + d, nullptr, sc,
            hd, dq, dq, NTOK, (long)hd, (long)hd, (long)NTOK * NTOK,
            0, 0, nullptr, 0);
        softmax_rows<<<HEADS * NTOK, 64, 0, stream>>>(sc, attnb, scale);
        // o = attn @ V^T (bf16), batched over heads
        gemm64<<<dim3(hd / 64, 6, HEADS), 256, 0, stream>>>(
            attnb, vtb, nullptr, ob,
            NTOK, NTOK, NTOK, d, (long)NTOK * NTOK, (long)hd * NTOK, (long)hd,
            0, 1, nullptr, 0);
        // out-proj (fp32) + LN
        gemm64<<<dim3(d / 64, 6), 256, 0, stream>>>(
            ob, wo + (long)l * d * d, out_b + l * d, t2,
            d, d, d, d, 0, 0, 0, 0, 0, nullptr, 0);
        add_ln<<<NTOK, 256, 0, stream>>>(x, xb, t2, ln1_s + l * d, ln1_b + l * d, d);
        // ff1 (relu, bf16), ff2 (fp32) + LN
        gemm64<<<dim3(2048 / 64, 6), 256, 0, stream>>>(
            xb, w1 + (long)l * 2048 * d, ff1_b + l * 2048, t1b,
            d, d, d, 2048, 0, 0, 0, 1, 1, nullptr, 0);
        gemm64<<<dim3(d / 64, 6), 256, 0, stream>>>(
            t1b, w2 + (long)l * d * 2048, ff2_b + l * d, t2,
            2048, 2048, 2048, d, 0, 0, 0, 0, 0, nullptr, 0);
        add_ln<<<NTOK, 256, 0, stream>>>(x, xb, t2, ln2_s + l * d, ln2_b + l * d, d);
    }
}

extern "C" void kernel_launch(void* const* d_in, const int* in_sizes, int n_in,
                              void* d_out, int out_size, void* d_ws, size_t ws_size,
                              hipStream_t stream)
{
    const float* text_emb   = (const float*)d_in[0];
    const float* vision_emb = (const float*)d_in[1];
    const int*   gt         = (const int*)  d_in[2];
    const float* t_qkv_w = (const float*)d_in[3];
    const float* t_qkv_b = (const float*)d_in[4];
    const float* t_out_w = (const float*)d_in[5];
    const float* t_out_b = (const float*)d_in[6];
    const float* t_ln1_s = (const float*)d_in[7];
    const float* t_ln1_b = (const float*)d_in[8];
    const float* t_ff1_w = (const float*)d_in[9];
    const float* t_ff1_b = (const float*)d_in[10];
    const float* t_ff2_w = (const float*)d_in[11];
    const float* t_ff2_b = (const float*)d_in[12];
    const float* t_ln2_s = (const float*)d_in[13];
    const float* t_ln2_b = (const float*)d_in[14];
    const float* c_qkv_w = (const float*)d_in[15];
    const float* c_qkv_b = (const float*)d_in[16];
    const float* c_out_w = (const float*)d_in[17];
    const float* c_out_b = (const float*)d_in[18];
    const float* c_ln1_s = (const float*)d_in[19];
    const float* c_ln1_b = (const float*)d_in[20];
    const float* c_ff1_w = (const float*)d_in[21];
    const float* c_ff1_b = (const float*)d_in[22];
    const float* c_ff2_w = (const float*)d_in[23];
    const float* c_ff2_b = (const float*)d_in[24];
    const float* c_ln2_s = (const float*)d_in[25];
    const float* c_ln2_b = (const float*)d_in[26];
    const float* lin_w   = (const float*)d_in[27];
    const float* lin_b   = (const float*)d_in[28];
    float* out = (float*)d_out;

    // ---- workspace layout ----
    float* ws = (float*)d_ws;
    float* xt      = ws;                 // 384*768
    float* all     = xt + 294912;        // 384*1536
    float* t2      = all + 589824;       // 384*1536 (max)
    float* sc      = t2 + 589824;        // 4*384*384 fp32
    float* abuf    = sc + 589824;
    float* cbuf    = abuf + 768;
    float* rowsum  = cbuf + 768;
    float* rowcell = rowsum + 384;
    float* colsum  = rowcell + 384;      // fp32 total 2067072
    unsigned short* ub = (unsigned short*)(ws + 2067072);
    unsigned short* xtb   = ub;                  // 294912
    unsigned short* allb  = xtb + 294912;        // 589824
    unsigned short* qkvb  = allb + 589824;       // 384*4608
    unsigned short* attnb = qkvb + 1769472;      // 4*384*384
    unsigned short* vtb   = attnb + 589824;      // 1536*384 (max)
    unsigned short* ob    = vtb + 589824;        // 589824
    unsigned short* t1b   = ob + 589824;         // 384*2048
    unsigned short* wb    = t1b + 786432;        // 42467328 bf16 weights

    // ---- weight conversion (one fused launch, nt loads) ----
    convert_weights<<<(WTOT / 16 + 255) / 256, 256, 0, stream>>>(
        t_qkv_w, t_out_w, t_ff1_w, t_ff2_w,
        c_qkv_w, c_out_w, c_ff1_w, c_ff2_w, wb);

    // ---- text encoder (d = 768) ----
    initx_k<<<(294912 + 255) / 256, 256, 0, stream>>>(text_emb, xt, xtb, 294912);
    run_encoder(xt, xtb, 768,
                wb + WO0, wb + WO1, wb + WO2, wb + WO3,
                t_qkv_b, t_out_b, t_ln1_s, t_ln1_b,
                t_ff1_b, t_ff2_b, t_ln2_s, t_ln2_b,
                qkvb, sc, attnb, vtb, ob, t1b, t2, stream);

    // ---- concat -> combined encoder (d = 1536) ----
    concat_k<<<(589824 + 255) / 256, 256, 0, stream>>>(xt, vision_emb, all, allb);
    run_encoder(all, allb, 1536,
                wb + WO4, wb + WO5, wb + WO6, wb + WO7,
                c_qkv_b, c_out_b, c_ln1_s, c_ln1_b,
                c_ff1_b, c_ff2_b, c_ln2_s, c_ln2_b,
                qkvb, sc, attnb, vtb, ob, t1b, t2, stream);

    // ---- head ----
    head_ac<<<NTOK, 256, 0, stream>>>(all, lin_w, lin_b, abuf, cbuf);
    head_probs<<<NTOK, 384, 0, stream>>>(abuf, cbuf, gt, out, rowsum, rowcell);
    colsum_k<<<NTOK, 64, 0, stream>>>(out, colsum);
    finalize_k<<<1, 384, 0, stream>>>(rowcell, rowsum, colsum, out);
}

// Round 12
// 505.668 us; speedup vs baseline: 1.2019x; 1.0018x over previous
//
#include <hip/hip_runtime.h>
#include <hip/hip_bf16.h>
#include <math.h>

#define NTOK 384
#define HEADS 4

typedef __attribute__((ext_vector_type(8))) short bf16x8;
typedef __attribute__((ext_vector_type(4))) float f32x4;

__device__ __forceinline__ unsigned short f2b(float f) {
    union { float f; unsigned int u; } v; v.f = f;
    unsigned int r = (v.u + 0x7fff + ((v.u >> 16) & 1)) >> 16;  // RNE
    return (unsigned short)r;
}

// async 16B global -> LDS (wave-uniform LDS base; HW adds lane*16)
__device__ __forceinline__ void g2l16(const void* g, void* l) {
    __builtin_amdgcn_global_load_lds(
        (const __attribute__((address_space(1))) unsigned int*)g,
        (__attribute__((address_space(3))) unsigned int*)l, 16, 0, 0);
}

// ---------------------------------------------------------------------------
// 64x64-tile MFMA bf16 GEMM, batched over z (r4-proven champion config).
// Block 256 thr = 4 waves (2x2, 32x32 each). BK=64, TRIPLE-buffered LDS,
// depth-2 counted-vmcnt pipeline: vmcnt(4) keeps the next tile's 4
// global_load_lds in flight across the barrier. Depth-3 measured
// null-to-negative (r11): per-iter floor is barrier+ds_read->MFMA chain,
// not load return — do not deepen further.
// ---------------------------------------------------------------------------
__device__ __forceinline__ void stage64(
    const unsigned short* __restrict__ g, int row0, int k0, int ld,
    char* region, int wid, int lane)
{
    int c = wid * 64 + lane;                 // chunk 0..255
    int row = c >> 2, p = c & 3;
    int kc = (p - (row >> 1)) & 3;
    g2l16(g + (long)(row0 + row) * ld + k0 + kc * 8,
          region + (wid * 64) * 16);         // wave-uniform base
}

__device__ __forceinline__ void stage_tile(
    const unsigned short* __restrict__ A, const unsigned short* __restrict__ B,
    int row0, int col0, int k0, int lda, int ldb,
    char* buf, int wid, int lane)
{
    stage64(A, row0, k0,      lda, buf,         wid, lane);
    stage64(A, row0, k0 + 32, lda, buf +  4096, wid, lane);
    stage64(B, col0, k0,      ldb, buf +  8192, wid, lane);
    stage64(B, col0, k0 + 32, ldb, buf + 12288, wid, lane);
    __builtin_amdgcn_sched_barrier(0);       // keep the 4 loads contiguous
}

__global__ __launch_bounds__(256, 3) void gemm64(
    const unsigned short* __restrict__ A, const unsigned short* __restrict__ B,
    const float* __restrict__ bias, void* __restrict__ Cv,
    int K, int lda, int ldb, int ldc,
    long sA, long sB, long sC, int relu, int out_bf16,
    unsigned short* __restrict__ vt, int dv2)
{
    __shared__ char smem[3][16384];          // per buf: A0|A1|B0|B1 (4KB each)
    A += (long)blockIdx.z * sA;
    B += (long)blockIdx.z * sB;
    const int t = threadIdx.x, lane = t & 63, wid = t >> 6;
    const int wm = wid >> 1, wn = wid & 1;
    const int r16 = lane & 15, quad = lane >> 4;
    const int row0 = blockIdx.y * 64, col0 = blockIdx.x * 64;

    f32x4 acc[2][2] = {};
    const int NT = K >> 6;                   // K is a multiple of 64 here

    stage_tile(A, B, row0, col0, 0, lda, ldb, smem[0], wid, lane);
    if (NT > 1)
        stage_tile(A, B, row0, col0, 64, lda, ldb, smem[1], wid, lane);

    int cur = 0, sb = 2;
    for (int kt = 0; kt < NT; ++kt) {
        if (kt + 1 < NT) asm volatile("s_waitcnt vmcnt(4)" ::: "memory");
        else             asm volatile("s_waitcnt vmcnt(0) lgkmcnt(0)" ::: "memory");
        __builtin_amdgcn_s_barrier();
        if (kt + 2 < NT) {
            stage_tile(A, B, row0, col0, (kt + 2) * 64, lda, ldb,
                       smem[sb], wid, lane);
            sb = (sb == 2) ? 0 : sb + 1;
        }
        const char* cb = smem[cur];
        cur = (cur == 2) ? 0 : cur + 1;
        #pragma unroll
        for (int h = 0; h < 2; ++h) {
            bf16x8 af[2], bfv[2];
            #pragma unroll
            for (int rt = 0; rt < 2; ++rt) {
                int row = wm * 32 + rt * 16 + r16;
                int p = (quad + (row >> 1)) & 3;
                af[rt] = *reinterpret_cast<const bf16x8*>(
                    cb + h * 4096 + row * 64 + p * 16);
            }
            #pragma unroll
            for (int ct = 0; ct < 2; ++ct) {
                int col = wn * 32 + ct * 16 + r16;
                int p = (quad + (col >> 1)) & 3;
                bfv[ct] = *reinterpret_cast<const bf16x8*>(
                    cb + 8192 + h * 4096 + col * 64 + p * 16);
            }
            #pragma unroll
            for (int rt = 0; rt < 2; ++rt)
                #pragma unroll
                for (int ct = 0; ct < 2; ++ct)
                    acc[rt][ct] = __builtin_amdgcn_mfma_f32_16x16x32_bf16(
                        af[rt], bfv[ct], acc[rt][ct], 0, 0, 0);
        }
    }

    float* Cf = (float*)Cv;
    unsigned short* Cb = (unsigned short*)Cv;
    const long zoff = (long)blockIdx.z * sC;
    const int vwrite = (vt != nullptr) && (col0 >= dv2);
    #pragma unroll
    for (int rt = 0; rt < 2; ++rt) {
        #pragma unroll
        for (int ct = 0; ct < 2; ++ct) {
            f32x4 v = acc[rt][ct];
            int col = col0 + wn * 32 + ct * 16 + r16;
            float bi = bias ? bias[col] : 0.f;
            #pragma unroll
            for (int i = 0; i < 4; ++i) {
                v[i] += bi;
                if (relu) v[i] = fmaxf(v[i], 0.f);
            }
            int rbase = row0 + wm * 32 + rt * 16 + quad * 4;
            if (vwrite) {
                ushort4 p;
                p.x = f2b(v[0]); p.y = f2b(v[1]); p.z = f2b(v[2]); p.w = f2b(v[3]);
                *reinterpret_cast<ushort4*>(vt + (long)(col - dv2) * NTOK + rbase) = p;
            } else if (out_bf16) {
                #pragma unroll
                for (int i = 0; i < 4; ++i)
                    Cb[zoff + (long)(rbase + i) * ldc + col] = f2b(v[i]);
            } else {
                #pragma unroll
                for (int i = 0; i < 4; ++i)
                    Cf[zoff + (long)(rbase + i) * ldc + col] = v[i];
            }
        }
    }
}

// ---------------------------------------------------------------------------
// Fused fp32 -> bf16 conversion of all 8 weight tensors. 16 elems/thread;
// NON-TEMPORAL loads (via ext_vector f32x4 — HIP float4 is a class type the
// builtin rejects): fp32 sources are dead after this pass; keeping them out
// of L3 leaves the 85MB bf16 destination resident for the GEMMs.
// Measured (r11): 70 -> 63-65 us.
// ---------------------------------------------------------------------------
#define WO0 0u
#define WO1 3538944u
#define WO2 4718592u
#define WO3 7864320u
#define WO4 11010048u
#define WO5 25165824u
#define WO6 29884416u
#define WO7 36175872u
#define WTOT 42467328u

__global__ __launch_bounds__(256) void convert_weights(
    const float* __restrict__ s0, const float* __restrict__ s1,
    const float* __restrict__ s2, const float* __restrict__ s3,
    const float* __restrict__ s4, const float* __restrict__ s5,
    const float* __restrict__ s6, const float* __restrict__ s7,
    unsigned short* __restrict__ dst)
{
    unsigned int e = (blockIdx.x * 256u + threadIdx.x) * 16u;
    if (e >= WTOT) return;
    const float* src; unsigned int local;
    if      (e < WO1) { src = s0; local = e - WO0; }
    else if (e < WO2) { src = s1; local = e - WO1; }
    else if (e < WO3) { src = s2; local = e - WO2; }
    else if (e < WO4) { src = s3; local = e - WO3; }
    else if (e < WO5) { src = s4; local = e - WO4; }
    else if (e < WO6) { src = s5; local = e - WO5; }
    else if (e < WO7) { src = s6; local = e - WO6; }
    else              { src = s7; local = e - WO7; }
    f32x4 v0 = __builtin_nontemporal_load(reinterpret_cast<const f32x4*>(src + local));
    f32x4 v1 = __builtin_nontemporal_load(reinterpret_cast<const f32x4*>(src + local + 4));
    f32x4 v2 = __builtin_nontemporal_load(reinterpret_cast<const f32x4*>(src + local + 8));
    f32x4 v3 = __builtin_nontemporal_load(reinterpret_cast<const f32x4*>(src + local + 12));
    uint4 o0, o1;
    o0.x = (unsigned)f2b(v0[0]) | ((unsigned)f2b(v0[1]) << 16);
    o0.y = (unsigned)f2b(v0[2]) | ((unsigned)f2b(v0[3]) << 16);
    o0.z = (unsigned)f2b(v1[0]) | ((unsigned)f2b(v1[1]) << 16);
    o0.w = (unsigned)f2b(v1[2]) | ((unsigned)f2b(v1[3]) << 16);
    o1.x = (unsigned)f2b(v2[0]) | ((unsigned)f2b(v2[1]) << 16);
    o1.y = (unsigned)f2b(v2[2]) | ((unsigned)f2b(v2[3]) << 16);
    o1.z = (unsigned)f2b(v3[0]) | ((unsigned)f2b(v3[1]) << 16);
    o1.w = (unsigned)f2b(v3[2]) | ((unsigned)f2b(v3[3]) << 16);
    *reinterpret_cast<uint4*>(dst + e) = o0;
    *reinterpret_cast<uint4*>(dst + e + 8) = o1;
}

// ---------------------------------------------------------------------------
// Softmax over rows of length 384 (one wave per row); fp32 in, bf16 out.
// ---------------------------------------------------------------------------
__global__ __launch_bounds__(64) void softmax_rows(
    const float* __restrict__ S, unsigned short* __restrict__ P, float scale)
{
    const float* p = S + (long)blockIdx.x * NTOK;
    unsigned short* q = P + (long)blockIdx.x * NTOK;
    const int t = threadIdx.x;
    float vals[6];
    float vmax = -1e30f;
    #pragma unroll
    for (int i = 0; i < 6; ++i) {
        vals[i] = p[t + i * 64] * scale;
        vmax = fmaxf(vmax, vals[i]);
    }
    for (int off = 32; off; off >>= 1) vmax = fmaxf(vmax, __shfl_down(vmax, off));
    vmax = __shfl(vmax, 0);
    float sum = 0.f;
    #pragma unroll
    for (int i = 0; i < 6; ++i) { vals[i] = __expf(vals[i] - vmax); sum += vals[i]; }
    for (int off = 32; off; off >>= 1) sum += __shfl_down(sum, off);
    sum = __shfl(sum, 0);
    float inv = 1.f / sum;
    #pragma unroll
    for (int i = 0; i < 6; ++i) q[t + i * 64] = f2b(vals[i] * inv);
}

// ---------------------------------------------------------------------------
// x = LayerNorm(x + y) * s + b  (fp32), also writes bf16 copy xb.
// ---------------------------------------------------------------------------
__global__ __launch_bounds__(256) void add_ln(
    float* __restrict__ x, unsigned short* __restrict__ xb,
    const float* __restrict__ y,
    const float* __restrict__ s, const float* __restrict__ b, int d)
{
    float* xr = x + (long)blockIdx.x * d;
    unsigned short* xbr = xb + (long)blockIdx.x * d;
    const float* yr = y + (long)blockIdx.x * d;
    const int t = threadIdx.x;
    float s1 = 0.f, s2 = 0.f;
    for (int i = t; i < d; i += 256) {
        float v = xr[i] + yr[i];
        s1 += v; s2 += v * v;
    }
    for (int off = 32; off; off >>= 1) { s1 += __shfl_down(s1, off); s2 += __shfl_down(s2, off); }
    __shared__ float r1[4], r2[4];
    int w = t >> 6;
    if ((t & 63) == 0) { r1[w] = s1; r2[w] = s2; }
    __syncthreads();
    if (t == 0) {
        float a = 0.f, c = 0.f;
        for (int i = 0; i < 4; ++i) { a += r1[i]; c += r2[i]; }
        r1[0] = a; r2[0] = c;
    }
    __syncthreads();
    float mean = r1[0] / d;
    float var = r2[0] / d - mean * mean;
    float rstd = rsqrtf(var + 1e-5f);
    for (int i = t; i < d; i += 256) {
        float v = (xr[i] + yr[i] - mean) * rstd * s[i] + b[i];
        xr[i] = v;
        xbr[i] = f2b(v);
    }
}

// ---------------------------------------------------------------------------
// init / concat (write fp32 + bf16 copies)
// ---------------------------------------------------------------------------
__global__ void initx_k(const float* __restrict__ src, float* __restrict__ dst,
                        unsigned short* __restrict__ dstb, int n)
{
    int i = blockIdx.x * blockDim.x + threadIdx.x;
    if (i < n) { float v = src[i]; dst[i] = v; dstb[i] = f2b(v); }
}

__global__ void concat_k(const float* __restrict__ te, const float* __restrict__ ve,
                         float* __restrict__ all, unsigned short* __restrict__ allb)
{
    int i = blockIdx.x * blockDim.x + threadIdx.x;
    if (i >= NTOK * 1536) return;
    int r = i / 1536, c = i % 1536;
    float v = (c < 768) ? te[r * 768 + c] : ve[r * 768 + (c - 768)];
    all[i] = v;
    allb[i] = f2b(v);
}

// ---------------------------------------------------------------------------
// head kernels (fp32)
// ---------------------------------------------------------------------------
__global__ __launch_bounds__(256) void head_ac(
    const float* __restrict__ all, const float* __restrict__ lin_w,
    const float* __restrict__ lin_b, float* __restrict__ a, float* __restrict__ c)
{
    const int i = blockIdx.x, t = threadIdx.x;
    const float* xr = all + (long)i * 1536;
    float s0 = 0.f, s1 = 0.f, s2 = 0.f, s3 = 0.f;
    for (int e = t; e < 1536; e += 256) {
        float v = xr[e];
        s0 += v * lin_w[e];
        s1 += v * lin_w[3072 + e];
        s2 += v * lin_w[1536 + e];
        s3 += v * lin_w[4608 + e];
    }
    for (int off = 32; off; off >>= 1) {
        s0 += __shfl_down(s0, off); s1 += __shfl_down(s1, off);
        s2 += __shfl_down(s2, off); s3 += __shfl_down(s3, off);
    }
    __shared__ float r[4][4];
    int w = t >> 6;
    if ((t & 63) == 0) { r[0][w] = s0; r[1][w] = s1; r[2][w] = s2; r[3][w] = s3; }
    __syncthreads();
    if (t == 0) {
        float t0 = 0.f, t1 = 0.f, t2 = 0.f, t3 = 0.f;
        for (int k = 0; k < 4; ++k) { t0 += r[0][k]; t1 += r[1][k]; t2 += r[2][k]; t3 += r[3][k]; }
        a[i * 2 + 0] = t0 + lin_b[0];
        a[i * 2 + 1] = t1 + lin_b[1];
        c[i * 2 + 0] = t2;
        c[i * 2 + 1] = t3;
    }
}

__global__ __launch_bounds__(384) void head_probs(
    const float* __restrict__ a, const float* __restrict__ c,
    const int* __restrict__ gt, float* __restrict__ probs,
    float* __restrict__ rowsum, float* __restrict__ rowcell)
{
    const int i = blockIdx.x, j = threadIdx.x;
    float l0 = a[i * 2 + 0] + c[j * 2 + 0];
    float l1 = a[i * 2 + 1] + c[j * 2 + 1];
    float m = fmaxf(l0, l1);
    float e0 = __expf(l0 - m), e1 = __expf(l1 - m);
    float inv = 1.f / (e0 + e1);
    float p0 = e0 * inv, p1 = e1 * inv;
    long base = ((long)i * NTOK + j) * 2;
    probs[base] = p0;
    probs[base + 1] = p1;
    float m2 = fmaxf(p0, p1);
    float z = m2 + __logf(__expf(p0 - m2) + __expf(p1 - m2));
    int g = gt[i * NTOK + j];
    float cell = z - (g ? p1 : p0);
    float cs = cell, ps = p1;
    for (int off = 32; off; off >>= 1) { cs += __shfl_down(cs, off); ps += __shfl_down(ps, off); }
    __shared__ float rc[6], rs[6];
    int w = j >> 6;
    if ((j & 63) == 0) { rc[w] = cs; rs[w] = ps; }
    __syncthreads();
    if (j == 0) {
        float csum = 0.f, psum = 0.f;
        for (int k = 0; k < 6; ++k) { csum += rc[k]; psum += rs[k]; }
        rowcell[i] = csum * (1.f / NTOK);
        rowsum[i] = psum;
    }
}

__global__ __launch_bounds__(64) void colsum_k(const float* __restrict__ probs,
                                               float* __restrict__ colsum)
{
    const int j = blockIdx.x, t = threadIdx.x;
    float s = 0.f;
    for (int i = t; i < NTOK; i += 64)
        s += probs[((long)i * NTOK + j) * 2 + 1];
    for (int off = 32; off; off >>= 1) s += __shfl_down(s, off);
    if (t == 0) colsum[j] = s;
}

__global__ __launch_bounds__(384) void finalize_k(
    const float* __restrict__ rowcell, const float* __restrict__ rowsum,
    const float* __restrict__ colsum, float* __restrict__ out)
{
    const int t = threadIdx.x;
    float cls = rowcell[t];
    float ee = (t < NTOK - 1) ? fabsf(rowsum[t] + colsum[t] - 1.f) : 0.f;
    for (int off = 32; off; off >>= 1) { cls += __shfl_down(cls, off); ee += __shfl_down(ee, off); }
    __shared__ float rc[6], re[6];
    int w = t >> 6;
    if ((t & 63) == 0) { rc[w] = cls; re[w] = ee; }
    __syncthreads();
    if (t == 0) {
        float a = 0.f, b = 0.f;
        for (int k = 0; k < 6; ++k) { a += rc[k]; b += re[k]; }
        out[NTOK * NTOK * 2 + 0] = a;
        out[NTOK * NTOK * 2 + 1] = b;
    }
}

// ---------------------------------------------------------------------------
// host-side encoder driver (bf16 weights, 64-tile staged gemms)
// ---------------------------------------------------------------------------
static void run_encoder(float* x, unsigned short* xb, int d,
                        const unsigned short* wq, const unsigned short* wo,
                        const unsigned short* w1, const unsigned short* w2,
                        const float* qkv_b, const float* out_b,
                        const float* ln1_s, const float* ln1_b,
                        const float* ff1_b, const float* ff2_b,
                        const float* ln2_s, const float* ln2_b,
                        unsigned short* qkvb, float* sc, unsigned short* attnb,
                        unsigned short* vtb, unsigned short* ob,
                        unsigned short* t1b, float* t2,
                        hipStream_t stream)
{
    const int dq = 3 * d;
    const int hd = d / HEADS;
    const float scale = 1.0f / sqrtf((float)hd);
    for (int l = 0; l < 2; ++l) {
        // qkv = x @ Wqkv^T + b (bf16; V block written transposed to vtb)
        gemm64<<<dim3(dq / 64, 6), 256, 0, stream>>>(
            xb, wq + (long)l * dq * d, qkv_b + l * dq, qkvb,
            d, d, d, dq, 0, 0, 0, 0, 1, vtb, 2 * d);
        // scores = Q @ K^T (fp32), batched over heads
        gemm64<<<dim3(6, 6, HEADS), 256, 0, stream>>>(
            qkvb, qkvb + d, nullptr, sc,
            hd, dq, dq, NTOK, (long)hd, (long)hd, (long)NTOK * NTOK,
            0, 0, nullptr, 0);
        softmax_rows<<<HEADS * NTOK, 64, 0, stream>>>(sc, attnb, scale);
        // o = attn @ V^T (bf16), batched over heads
        gemm64<<<dim3(hd / 64, 6, HEADS), 256, 0, stream>>>(
            attnb, vtb, nullptr, ob,
            NTOK, NTOK, NTOK, d, (long)NTOK * NTOK, (long)hd * NTOK, (long)hd,
            0, 1, nullptr, 0);
        // out-proj (fp32) + LN
        gemm64<<<dim3(d / 64, 6), 256, 0, stream>>>(
            ob, wo + (long)l * d * d, out_b + l * d, t2,
            d, d, d, d, 0, 0, 0, 0, 0, nullptr, 0);
        add_ln<<<NTOK, 256, 0, stream>>>(x, xb, t2, ln1_s + l * d, ln1_b + l * d, d);
        // ff1 (relu, bf16), ff2 (fp32) + LN
        gemm64<<<dim3(2048 / 64, 6), 256, 0, stream>>>(
            xb, w1 + (long)l * 2048 * d, ff1_b + l * 2048, t1b,
            d, d, d, 2048, 0, 0, 0, 1, 1, nullptr, 0);
        gemm64<<<dim3(d / 64, 6), 256, 0, stream>>>(
            t1b, w2 + (long)l * d * 2048, ff2_b + l * d, t2,
            2048, 2048, 2048, d, 0, 0, 0, 0, 0, nullptr, 0);
        add_ln<<<NTOK, 256, 0, stream>>>(x, xb, t2, ln2_s + l * d, ln2_b + l * d, d);
    }
}

extern "C" void kernel_launch(void* const* d_in, const int* in_sizes, int n_in,
                              void* d_out, int out_size, void* d_ws, size_t ws_size,
                              hipStream_t stream)
{
    const float* text_emb   = (const float*)d_in[0];
    const float* vision_emb = (const float*)d_in[1];
    const int*   gt         = (const int*)  d_in[2];
    const float* t_qkv_w = (const float*)d_in[3];
    const float* t_qkv_b = (const float*)d_in[4];
    const float* t_out_w = (const float*)d_in[5];
    const float* t_out_b = (const float*)d_in[6];
    const float* t_ln1_s = (const float*)d_in[7];
    const float* t_ln1_b = (const float*)d_in[8];
    const float* t_ff1_w = (const float*)d_in[9];
    const float* t_ff1_b = (const float*)d_in[10];
    const float* t_ff2_w = (const float*)d_in[11];
    const float* t_ff2_b = (const float*)d_in[12];
    const float* t_ln2_s = (const float*)d_in[13];
    const float* t_ln2_b = (const float*)d_in[14];
    const float* c_qkv_w = (const float*)d_in[15];
    const float* c_qkv_b = (const float*)d_in[16];
    const float* c_out_w = (const float*)d_in[17];
    const float* c_out_b = (const float*)d_in[18];
    const float* c_ln1_s = (const float*)d_in[19];
    const float* c_ln1_b = (const float*)d_in[20];
    const float* c_ff1_w = (const float*)d_in[21];
    const float* c_ff1_b = (const float*)d_in[22];
    const float* c_ff2_w = (const float*)d_in[23];
    const float* c_ff2_b = (const float*)d_in[24];
    const float* c_ln2_s = (const float*)d_in[25];
    const float* c_ln2_b = (const float*)d_in[26];
    const float* lin_w   = (const float*)d_in[27];
    const float* lin_b   = (const float*)d_in[28];
    float* out = (float*)d_out;

    // ---- workspace layout ----
    float* ws = (float*)d_ws;
    float* xt      = ws;                 // 384*768
    float* all     = xt + 294912;        // 384*1536
    float* t2      = all + 589824;       // 384*1536 (max)
    float* sc      = t2 + 589824;        // 4*384*384 fp32
    float* abuf    = sc + 589824;
    float* cbuf    = abuf + 768;
    float* rowsum  = cbuf + 768;
    float* rowcell = rowsum + 384;
    float* colsum  = rowcell + 384;      // fp32 total 2067072
    unsigned short* ub = (unsigned short*)(ws + 2067072);
    unsigned short* xtb   = ub;                  // 294912
    unsigned short* allb  = xtb + 294912;        // 589824
    unsigned short* qkvb  = allb + 589824;       // 384*4608
    unsigned short* attnb = qkvb + 1769472;      // 4*384*384
    unsigned short* vtb   = attnb + 589824;      // 1536*384 (max)
    unsigned short* ob    = vtb + 589824;        // 589824
    unsigned short* t1b   = ob + 589824;         // 384*2048
    unsigned short* wb    = t1b + 786432;        // 42467328 bf16 weights

    // ---- weight conversion (one fused launch, nt loads) ----
    convert_weights<<<(WTOT / 16 + 255) / 256, 256, 0, stream>>>(
        t_qkv_w, t_out_w, t_ff1_w, t_ff2_w,
        c_qkv_w, c_out_w, c_ff1_w, c_ff2_w, wb);

    // ---- text encoder (d = 768) ----
    initx_k<<<(294912 + 255) / 256, 256, 0, stream>>>(text_emb, xt, xtb, 294912);
    run_encoder(xt, xtb, 768,
                wb + WO0, wb + WO1, wb + WO2, wb + WO3,
                t_qkv_b, t_out_b, t_ln1_s, t_ln1_b,
                t_ff1_b, t_ff2_b, t_ln2_s, t_ln2_b,
                qkvb, sc, attnb, vtb, ob, t1b, t2, stream);

    // ---- concat -> combined encoder (d = 1536) ----
    concat_k<<<(589824 + 255) / 256, 256, 0, stream>>>(xt, vision_emb, all, allb);
    run_encoder(all, allb, 1536,
                wb + WO4, wb + WO5, wb + WO6, wb + WO7,
                c_qkv_b, c_out_b, c_ln1_s, c_ln1_b,
                c_ff1_b, c_ff2_b, c_ln2_s, c_ln2_b,
                qkvb, sc, attnb, vtb, ob, t1b, t2, stream);

    // ---- head ----
    head_ac<<<NTOK, 256, 0, stream>>>(all, lin_w, lin_b, abuf, cbuf);
    head_probs<<<NTOK, 384, 0, stream>>>(abuf, cbuf, gt, out, rowsum, rowcell);
    colsum_k<<<NTOK, 64, 0, stream>>>(out, colsum);
    finalize_k<<<1, 384, 0, stream>>>(rowcell, rowsum, colsum, out);
}